// Round 12
// baseline (253.629 us; speedup 1.0000x reference)
//
#include <hip/hip_runtime.h>

#define B_   16
#define C_   64
#define HW_  65536
#define CHW_ (C_ * HW_)   // 4194304 elements per batch

typedef short bf16x8 __attribute__((ext_vector_type(8)));
typedef float f32x4v __attribute__((ext_vector_type(4)));

// fp32 -> bf16 round-to-nearest-even
__device__ __forceinline__ unsigned short bfrne(float f) {
    unsigned int u = __float_as_uint(f);
    u += 0x7FFFu + ((u >> 16) & 1u);
    return (unsigned short)(u >> 16);
}
__device__ __forceinline__ float bfdec(unsigned short h) {
    return __uint_as_float((unsigned int)h << 16);
}

// ---------------------------------------------------------------------------
// Kernel 1 v6 (split-bf16 MFMA, 64x64 wave tile, streamed-B register diet):
// S[b,c,d] = sum_n A[c][n]*B[n][d];  x = hi+lo bf16, S ~= hh+hl+lh.
// Same tiling as v4 (R9, 95us) but B hi/lo fragments are converted one dt at
// a time (saves ~24 live VGPRs) so the kernel fits launch_bounds(256,3):
// 12 waves/CU instead of 8 for the same tile and traffic.
// ---------------------------------------------------------------------------
__global__ __launch_bounds__(256, 3) void k1_gram(const float* __restrict__ x,
                                                  float* __restrict__ partial,
                                                  int nch, int nb) {
    const int ch  = blockIdx.x;
    const int b   = blockIdx.y;
    const int t   = threadIdx.x;
    const int w   = t >> 6;
    const int l   = t & 63;
    const int g   = l >> 4;      // k-octet selector
    const int col = l & 15;      // A-row / B-col within 16-tile

    const float* xb = x + (size_t)b * CHW_;
    const int nq  = nb >> 2;     // n per wave
    const int nw0 = ch * nb + w * nq;

    f32x4v acc[4][4];            // [ct][dt]
    #pragma unroll
    for (int ct = 0; ct < 4; ct++)
        #pragma unroll
        for (int dt = 0; dt < 4; dt++) acc[ct][dt] = (f32x4v)(0.f);

    for (int ns = nw0; ns < nw0 + nq; ns += 32) {
        // --- A fragments: lane holds A[16ct+col][ns+8g+j], j=0..7 ---
        bf16x8 ahi[4], alo[4];
        #pragma unroll
        for (int ct = 0; ct < 4; ct++) {
            const float* ap = xb + (size_t)(16 * ct + col) * HW_ + ns + 8 * g;
            float av[8];
            *(float4*)&av[0] = *(const float4*)ap;
            *(float4*)&av[4] = *(const float4*)(ap + 4);
            #pragma unroll
            for (int j = 0; j < 8; j++) {
                const unsigned short h = bfrne(av[j]);
                ahi[ct][j] = (short)h;
                alo[ct][j] = (short)bfrne(av[j] - bfdec(h));
            }
        }
        // --- B: stream one dt at a time (register diet) ---
        #pragma unroll
        for (int dt = 0; dt < 4; dt++) {
            const float* bp = xb + (size_t)(ns + 8 * g) * C_ + 16 * dt + col;
            float bv[8];
            #pragma unroll
            for (int j = 0; j < 8; j++) bv[j] = bp[j * C_];
            bf16x8 bhi, blo;
            #pragma unroll
            for (int j = 0; j < 8; j++) {
                const unsigned short h = bfrne(bv[j]);
                bhi[j] = (short)h;
                blo[j] = (short)bfrne(bv[j] - bfdec(h));
            }
            #pragma unroll
            for (int ct = 0; ct < 4; ct++) {
                acc[ct][dt] = __builtin_amdgcn_mfma_f32_16x16x32_bf16(
                    ahi[ct], bhi, acc[ct][dt], 0, 0, 0);
                acc[ct][dt] = __builtin_amdgcn_mfma_f32_16x16x32_bf16(
                    ahi[ct], blo, acc[ct][dt], 0, 0, 0);
                acc[ct][dt] = __builtin_amdgcn_mfma_f32_16x16x32_bf16(
                    alo[ct], bhi, acc[ct][dt], 0, 0, 0);
            }
        }
    }

    // --- cross-wave reduce: D[16ct+4g+r][16dt+col] ---
    __shared__ float sred[4096];
    for (int wr = 0; wr < 4; wr++) {
        if (w == wr) {
            #pragma unroll
            for (int ct = 0; ct < 4; ct++)
                #pragma unroll
                for (int dt = 0; dt < 4; dt++)
                    #pragma unroll
                    for (int r = 0; r < 4; r++) {
                        const int idx = (16 * ct + 4 * g + r) * 64 + 16 * dt + col;
                        if (wr == 0) sred[idx] = acc[ct][dt][r];
                        else         sred[idx] += acc[ct][dt][r];
                    }
        }
        __syncthreads();
    }

    float* pb = partial + (size_t)(b * nch + ch) * 4096;
    for (int i = 4 * t; i < 4096; i += 1024)
        *(float4*)&pb[i] = *(const float4*)&sred[i];
}

// ---------------------------------------------------------------------------
// Kernel 2 v3: reduce partials + softmax (unchanged).
// Writes mbf[b,c,d] = bf16( softmax(S)[b,c,d] + (c==d) ).
// ---------------------------------------------------------------------------
__global__ __launch_bounds__(256) void k2_softmax(const float* __restrict__ partial,
                                                  unsigned short* __restrict__ mbf,
                                                  int nch) {
    const int c = blockIdx.x;
    const int b = blockIdx.y;
    const int t = threadIdx.x;
    const int w = t >> 6;
    const int d = t & 63;

    float s = 0.f;
    for (int ch = w; ch < nch; ch += 4)
        s += partial[(size_t)(b * nch + ch) * 4096 + c * 64 + d];

    __shared__ float red[256];
    red[t] = s;
    __syncthreads();
    if (w == 0) {
        s = red[d] + red[64 + d] + red[128 + d] + red[192 + d];
        float m = s;
        #pragma unroll
        for (int off = 32; off > 0; off >>= 1) m = fmaxf(m, __shfl_xor(m, off));
        const float e = expf(s - m);
        float sum = e;
        #pragma unroll
        for (int off = 32; off > 0; off >>= 1) sum += __shfl_xor(sum, off);
        mbf[(size_t)b * 4096 + c * 64 + d] = bfrne(e / sum + (c == d ? 1.f : 0.f));
    }
}

// ---------------------------------------------------------------------------
// Kernel 3 v6 (MFMA bf16 — proven R8 version, unchanged):
// out[b,c,n] = sum_d M[c,d] * X[b, d*HW + n]
// ---------------------------------------------------------------------------
__global__ __launch_bounds__(256, 3) void k3_out(const float* __restrict__ x,
                                                 const unsigned short* __restrict__ mbf,
                                                 float* __restrict__ out) {
    const int nbk  = blockIdx.x;
    const int b    = blockIdx.y;
    const int t    = threadIdx.x;
    const int w    = t >> 6;
    const int l    = t & 63;
    const int g    = l >> 4;
    const int col  = l & 15;

    const int n0 = nbk * 256 + w * 64;
    const float* xb = x + (size_t)b * CHW_;

    bf16x8 afr[4][2];
    const unsigned short* mb = mbf + (size_t)b * 4096;
    #pragma unroll
    for (int ct = 0; ct < 4; ct++)
        #pragma unroll
        for (int ks = 0; ks < 2; ks++)
            afr[ct][ks] = *(const bf16x8*)(mb + (16 * ct + col) * 64 + 32 * ks + 8 * g);

    f32x4v acc[4][4];   // [ct][nt]
    #pragma unroll
    for (int ct = 0; ct < 4; ct++)
        #pragma unroll
        for (int nt = 0; nt < 4; nt++)
            acc[ct][nt] = (f32x4v)(0.f);

    #pragma unroll
    for (int nt = 0; nt < 4; nt++) {
        const float* xpf = xb + n0 + 16 * nt + col;
        float xv[2][8];
        #pragma unroll
        for (int ks = 0; ks < 2; ks++)
            #pragma unroll
            for (int j = 0; j < 8; j++)
                xv[ks][j] = xpf[(size_t)(32 * ks + 8 * g + j) * HW_];

        bf16x8 bfr[2];
        #pragma unroll
        for (int ks = 0; ks < 2; ks++)
            #pragma unroll
            for (int j = 0; j < 8; j++)
                bfr[ks][j] = (short)bfrne(xv[ks][j]);

        #pragma unroll
        for (int ct = 0; ct < 4; ct++)
            #pragma unroll
            for (int ks = 0; ks < 2; ks++)
                acc[ct][nt] = __builtin_amdgcn_mfma_f32_16x16x32_bf16(
                    afr[ct][ks], bfr[ks], acc[ct][nt], 0, 0, 0);
    }

    float* ob = out + (size_t)b * CHW_;
    #pragma unroll
    for (int ct = 0; ct < 4; ct++)
        #pragma unroll
        for (int nt = 0; nt < 4; nt++)
            #pragma unroll
            for (int r = 0; r < 4; r++)
                ob[(size_t)(16 * ct + 4 * g + r) * HW_ + n0 + 16 * nt + col] =
                    acc[ct][nt][r];
}

// ---------------------------------------------------------------------------
extern "C" void kernel_launch(void* const* d_in, const int* in_sizes, int n_in,
                              void* d_out, int out_size, void* d_ws, size_t ws_size,
                              hipStream_t stream) {
    const float* x = (const float*)d_in[0];
    float* out = (float*)d_out;

    float* wsf          = (float*)d_ws;
    unsigned short* mbf = (unsigned short*)wsf;      // B*4096 ushorts (128KB)
    float* partial      = wsf + (size_t)B_ * 4096;   // B*nch*4096 floats

    int nch = 64;
    while (nch > 1) {
        size_t need = (size_t)B_ * 4096 * sizeof(float)
                    + (size_t)B_ * nch * 4096 * sizeof(float);
        if (need <= ws_size) break;
        nch >>= 1;
    }
    const int nb = HW_ / nch;

    k1_gram<<<dim3(nch, B_), 256, 0, stream>>>(x, partial, nch, nb);
    k2_softmax<<<dim3(C_, B_), 256, 0, stream>>>(partial, mbf, nch);
    k3_out<<<dim3(HW_ / 256, B_), 256, 0, stream>>>(x, mbf, out);
}

// Round 13
// 224.570 us; speedup vs baseline: 1.1294x; 1.1294x over previous
//
#include <hip/hip_runtime.h>

#define B_   16
#define C_   64
#define HW_  65536
#define CHW_ (C_ * HW_)   // 4194304 elements per batch

typedef short bf16x8 __attribute__((ext_vector_type(8)));
typedef float f32x4v __attribute__((ext_vector_type(4)));

// fp32 -> bf16 round-to-nearest-even
__device__ __forceinline__ unsigned short bfrne(float f) {
    unsigned int u = __float_as_uint(f);
    u += 0x7FFFu + ((u >> 16) & 1u);
    return (unsigned short)(u >> 16);
}
__device__ __forceinline__ float bfdec(unsigned short h) {
    return __uint_as_float((unsigned int)h << 16);
}

// ---------------------------------------------------------------------------
// Kernel 1 v4 (reverted to the proven R9 version — 95us).  Split-bf16 MFMA:
// S[b,c,d] = sum_n A[c][n]*B[n][d]; x = hi+lo bf16; S ~= hh+hl+lh.
// ALL fragments of an iteration are loaded before compute (max MLP) — the
// R10/R12 "register diet" variants each lost 1.5x by serializing loads.
// ---------------------------------------------------------------------------
__global__ __launch_bounds__(256, 2) void k1_gram(const float* __restrict__ x,
                                                  float* __restrict__ partial,
                                                  int nch, int nb) {
    const int ch  = blockIdx.x;
    const int b   = blockIdx.y;
    const int t   = threadIdx.x;
    const int w   = t >> 6;
    const int l   = t & 63;
    const int g   = l >> 4;      // k-octet selector
    const int col = l & 15;      // A-row / B-col within 16-tile

    const float* xb = x + (size_t)b * CHW_;
    const int nq  = nb >> 2;     // n per wave
    const int nw0 = ch * nb + w * nq;

    f32x4v acc[4][4];            // [ct][dt]
    #pragma unroll
    for (int ct = 0; ct < 4; ct++)
        #pragma unroll
        for (int dt = 0; dt < 4; dt++) acc[ct][dt] = (f32x4v)(0.f);

    for (int ns = nw0; ns < nw0 + nq; ns += 32) {
        // --- A fragments: lane holds A[16ct+col][ns+8g+j], j=0..7 ---
        bf16x8 ahi[4], alo[4];
        #pragma unroll
        for (int ct = 0; ct < 4; ct++) {
            const float* ap = xb + (size_t)(16 * ct + col) * HW_ + ns + 8 * g;
            float av[8];
            *(float4*)&av[0] = *(const float4*)ap;
            *(float4*)&av[4] = *(const float4*)(ap + 4);
            #pragma unroll
            for (int j = 0; j < 8; j++) {
                const unsigned short h = bfrne(av[j]);
                ahi[ct][j] = (short)h;
                alo[ct][j] = (short)bfrne(av[j] - bfdec(h));
            }
        }
        // --- B fragments: lane holds B[ns+8g+j][16dt+col], j=0..7 ---
        bf16x8 bhi[4], blo[4];
        #pragma unroll
        for (int dt = 0; dt < 4; dt++) {
            const float* bp = xb + (size_t)(ns + 8 * g) * C_ + 16 * dt + col;
            float bv[8];
            #pragma unroll
            for (int j = 0; j < 8; j++) bv[j] = bp[j * C_];
            #pragma unroll
            for (int j = 0; j < 8; j++) {
                const unsigned short h = bfrne(bv[j]);
                bhi[dt][j] = (short)h;
                blo[dt][j] = (short)bfrne(bv[j] - bfdec(h));
            }
        }
        // --- 48 MFMAs: hi*hi + hi*lo + lo*hi ---
        #pragma unroll
        for (int ct = 0; ct < 4; ct++)
            #pragma unroll
            for (int dt = 0; dt < 4; dt++) {
                acc[ct][dt] = __builtin_amdgcn_mfma_f32_16x16x32_bf16(
                    ahi[ct], bhi[dt], acc[ct][dt], 0, 0, 0);
                acc[ct][dt] = __builtin_amdgcn_mfma_f32_16x16x32_bf16(
                    ahi[ct], blo[dt], acc[ct][dt], 0, 0, 0);
                acc[ct][dt] = __builtin_amdgcn_mfma_f32_16x16x32_bf16(
                    alo[ct], bhi[dt], acc[ct][dt], 0, 0, 0);
            }
    }

    // --- cross-wave reduce: D[16ct+4g+r][16dt+col] ---
    __shared__ float sred[4096];
    for (int wr = 0; wr < 4; wr++) {
        if (w == wr) {
            #pragma unroll
            for (int ct = 0; ct < 4; ct++)
                #pragma unroll
                for (int dt = 0; dt < 4; dt++)
                    #pragma unroll
                    for (int r = 0; r < 4; r++) {
                        const int idx = (16 * ct + 4 * g + r) * 64 + 16 * dt + col;
                        if (wr == 0) sred[idx] = acc[ct][dt][r];
                        else         sred[idx] += acc[ct][dt][r];
                    }
        }
        __syncthreads();
    }

    float* pb = partial + (size_t)(b * nch + ch) * 4096;
    for (int i = 4 * t; i < 4096; i += 1024)
        *(float4*)&pb[i] = *(const float4*)&sred[i];
}

// ---------------------------------------------------------------------------
// Kernel 2 v3: reduce partials + softmax (unchanged).
// Writes mbf[b,c,d] = bf16( softmax(S)[b,c,d] + (c==d) ).
// ---------------------------------------------------------------------------
__global__ __launch_bounds__(256) void k2_softmax(const float* __restrict__ partial,
                                                  unsigned short* __restrict__ mbf,
                                                  int nch) {
    const int c = blockIdx.x;
    const int b = blockIdx.y;
    const int t = threadIdx.x;
    const int w = t >> 6;
    const int d = t & 63;

    float s = 0.f;
    for (int ch = w; ch < nch; ch += 4)
        s += partial[(size_t)(b * nch + ch) * 4096 + c * 64 + d];

    __shared__ float red[256];
    red[t] = s;
    __syncthreads();
    if (w == 0) {
        s = red[d] + red[64 + d] + red[128 + d] + red[192 + d];
        float m = s;
        #pragma unroll
        for (int off = 32; off > 0; off >>= 1) m = fmaxf(m, __shfl_xor(m, off));
        const float e = expf(s - m);
        float sum = e;
        #pragma unroll
        for (int off = 32; off > 0; off >>= 1) sum += __shfl_xor(sum, off);
        mbf[(size_t)b * 4096 + c * 64 + d] = bfrne(e / sum + (c == d ? 1.f : 0.f));
    }
}

// ---------------------------------------------------------------------------
// Kernel 3 v8 (v6 + full-tile load hoist): out[b,c,n] = sum_d M[c,d]*X[b,d,n]
// All 64 per-lane x loads issued before any convert/MFMA (xv[4][16], static
// indexing) -> 64 loads in flight per wave; launch_bounds(256,2) gives the
// allocator room (acc 64 + xv 64 + afr 32 VGPRs).
// ---------------------------------------------------------------------------
__global__ __launch_bounds__(256, 2) void k3_out(const float* __restrict__ x,
                                                 const unsigned short* __restrict__ mbf,
                                                 float* __restrict__ out) {
    const int nbk  = blockIdx.x;
    const int b    = blockIdx.y;
    const int t    = threadIdx.x;
    const int w    = t >> 6;
    const int l    = t & 63;
    const int g    = l >> 4;
    const int col  = l & 15;

    const int n0 = nbk * 256 + w * 64;
    const float* xb = x + (size_t)b * CHW_;

    bf16x8 afr[4][2];
    const unsigned short* mb = mbf + (size_t)b * 4096;
    #pragma unroll
    for (int ct = 0; ct < 4; ct++)
        #pragma unroll
        for (int ks = 0; ks < 2; ks++)
            afr[ct][ks] = *(const bf16x8*)(mb + (16 * ct + col) * 64 + 32 * ks + 8 * g);

    // --- hoist ALL x loads for the 64d x 64n wave tile ---
    float xv[4][16];   // [nt][8*ks+j]
    #pragma unroll
    for (int nt = 0; nt < 4; nt++) {
        const float* xpf = xb + n0 + 16 * nt + col;
        #pragma unroll
        for (int ks = 0; ks < 2; ks++)
            #pragma unroll
            for (int j = 0; j < 8; j++)
                xv[nt][8 * ks + j] = xpf[(size_t)(32 * ks + 8 * g + j) * HW_];
    }

    f32x4v acc[4][4];   // [ct][nt]
    #pragma unroll
    for (int ct = 0; ct < 4; ct++)
        #pragma unroll
        for (int nt = 0; nt < 4; nt++)
            acc[ct][nt] = (f32x4v)(0.f);

    #pragma unroll
    for (int nt = 0; nt < 4; nt++) {
        bf16x8 bfr[2];
        #pragma unroll
        for (int ks = 0; ks < 2; ks++)
            #pragma unroll
            for (int j = 0; j < 8; j++)
                bfr[ks][j] = (short)bfrne(xv[nt][8 * ks + j]);

        #pragma unroll
        for (int ct = 0; ct < 4; ct++)
            #pragma unroll
            for (int ks = 0; ks < 2; ks++)
                acc[ct][nt] = __builtin_amdgcn_mfma_f32_16x16x32_bf16(
                    afr[ct][ks], bfr[ks], acc[ct][nt], 0, 0, 0);
    }

    float* ob = out + (size_t)b * CHW_;
    #pragma unroll
    for (int ct = 0; ct < 4; ct++)
        #pragma unroll
        for (int nt = 0; nt < 4; nt++)
            #pragma unroll
            for (int r = 0; r < 4; r++)
                ob[(size_t)(16 * ct + 4 * g + r) * HW_ + n0 + 16 * nt + col] =
                    acc[ct][nt][r];
}

// ---------------------------------------------------------------------------
extern "C" void kernel_launch(void* const* d_in, const int* in_sizes, int n_in,
                              void* d_out, int out_size, void* d_ws, size_t ws_size,
                              hipStream_t stream) {
    const float* x = (const float*)d_in[0];
    float* out = (float*)d_out;

    float* wsf          = (float*)d_ws;
    unsigned short* mbf = (unsigned short*)wsf;      // B*4096 ushorts (128KB)
    float* partial      = wsf + (size_t)B_ * 4096;   // B*nch*4096 floats

    int nch = 64;
    while (nch > 1) {
        size_t need = (size_t)B_ * 4096 * sizeof(float)
                    + (size_t)B_ * nch * 4096 * sizeof(float);
        if (need <= ws_size) break;
        nch >>= 1;
    }
    const int nb = HW_ / nch;

    k1_gram<<<dim3(nch, B_), 256, 0, stream>>>(x, partial, nch, nb);
    k2_softmax<<<dim3(C_, B_), 256, 0, stream>>>(partial, mbf, nch);
    k3_out<<<dim3(HW_ / 256, B_), 256, 0, stream>>>(x, mbf, out);
}

// Round 14
// 209.091 us; speedup vs baseline: 1.2130x; 1.0740x over previous
//
#include <hip/hip_runtime.h>

#define B_   16
#define C_   64
#define HW_  65536
#define CHW_ (C_ * HW_)   // 4194304 elements per batch

typedef short bf16x8 __attribute__((ext_vector_type(8)));
typedef float f32x4v __attribute__((ext_vector_type(4)));

// fp32 -> bf16 round-to-nearest-even
__device__ __forceinline__ unsigned short bfrne(float f) {
    unsigned int u = __float_as_uint(f);
    u += 0x7FFFu + ((u >> 16) & 1u);
    return (unsigned short)(u >> 16);
}
__device__ __forceinline__ float bfdec(unsigned short h) {
    return __uint_as_float((unsigned int)h << 16);
}

// ---------------------------------------------------------------------------
// Kernel 1 v4 (proven R9 version, unchanged — 95us).  Split-bf16 MFMA:
// S[b,c,d] = sum_n A[c][n]*B[n][d]; x = hi+lo bf16; S ~= hh+hl+lh.
// ---------------------------------------------------------------------------
__global__ __launch_bounds__(256, 2) void k1_gram(const float* __restrict__ x,
                                                  float* __restrict__ partial,
                                                  int nch, int nb) {
    const int ch  = blockIdx.x;
    const int b   = blockIdx.y;
    const int t   = threadIdx.x;
    const int w   = t >> 6;
    const int l   = t & 63;
    const int g   = l >> 4;      // k-octet selector
    const int col = l & 15;      // A-row / B-col within 16-tile

    const float* xb = x + (size_t)b * CHW_;
    const int nq  = nb >> 2;     // n per wave
    const int nw0 = ch * nb + w * nq;

    f32x4v acc[4][4];            // [ct][dt]
    #pragma unroll
    for (int ct = 0; ct < 4; ct++)
        #pragma unroll
        for (int dt = 0; dt < 4; dt++) acc[ct][dt] = (f32x4v)(0.f);

    for (int ns = nw0; ns < nw0 + nq; ns += 32) {
        bf16x8 ahi[4], alo[4];
        #pragma unroll
        for (int ct = 0; ct < 4; ct++) {
            const float* ap = xb + (size_t)(16 * ct + col) * HW_ + ns + 8 * g;
            float av[8];
            *(float4*)&av[0] = *(const float4*)ap;
            *(float4*)&av[4] = *(const float4*)(ap + 4);
            #pragma unroll
            for (int j = 0; j < 8; j++) {
                const unsigned short h = bfrne(av[j]);
                ahi[ct][j] = (short)h;
                alo[ct][j] = (short)bfrne(av[j] - bfdec(h));
            }
        }
        bf16x8 bhi[4], blo[4];
        #pragma unroll
        for (int dt = 0; dt < 4; dt++) {
            const float* bp = xb + (size_t)(ns + 8 * g) * C_ + 16 * dt + col;
            float bv[8];
            #pragma unroll
            for (int j = 0; j < 8; j++) bv[j] = bp[j * C_];
            #pragma unroll
            for (int j = 0; j < 8; j++) {
                const unsigned short h = bfrne(bv[j]);
                bhi[dt][j] = (short)h;
                blo[dt][j] = (short)bfrne(bv[j] - bfdec(h));
            }
        }
        #pragma unroll
        for (int ct = 0; ct < 4; ct++)
            #pragma unroll
            for (int dt = 0; dt < 4; dt++) {
                acc[ct][dt] = __builtin_amdgcn_mfma_f32_16x16x32_bf16(
                    ahi[ct], bhi[dt], acc[ct][dt], 0, 0, 0);
                acc[ct][dt] = __builtin_amdgcn_mfma_f32_16x16x32_bf16(
                    ahi[ct], blo[dt], acc[ct][dt], 0, 0, 0);
                acc[ct][dt] = __builtin_amdgcn_mfma_f32_16x16x32_bf16(
                    alo[ct], bhi[dt], acc[ct][dt], 0, 0, 0);
            }
    }

    __shared__ float sred[4096];
    for (int wr = 0; wr < 4; wr++) {
        if (w == wr) {
            #pragma unroll
            for (int ct = 0; ct < 4; ct++)
                #pragma unroll
                for (int dt = 0; dt < 4; dt++)
                    #pragma unroll
                    for (int r = 0; r < 4; r++) {
                        const int idx = (16 * ct + 4 * g + r) * 64 + 16 * dt + col;
                        if (wr == 0) sred[idx] = acc[ct][dt][r];
                        else         sred[idx] += acc[ct][dt][r];
                    }
        }
        __syncthreads();
    }

    float* pb = partial + (size_t)(b * nch + ch) * 4096;
    for (int i = 4 * t; i < 4096; i += 1024)
        *(float4*)&pb[i] = *(const float4*)&sred[i];
}

// ---------------------------------------------------------------------------
// Kernel 2 v3: reduce partials + softmax (unchanged).
// Writes mbf[b,c,d] = bf16( softmax(S)[b,c,d] + (c==d) ).
// ---------------------------------------------------------------------------
__global__ __launch_bounds__(256) void k2_softmax(const float* __restrict__ partial,
                                                  unsigned short* __restrict__ mbf,
                                                  int nch) {
    const int c = blockIdx.x;
    const int b = blockIdx.y;
    const int t = threadIdx.x;
    const int w = t >> 6;
    const int d = t & 63;

    float s = 0.f;
    for (int ch = w; ch < nch; ch += 4)
        s += partial[(size_t)(b * nch + ch) * 4096 + c * 64 + d];

    __shared__ float red[256];
    red[t] = s;
    __syncthreads();
    if (w == 0) {
        s = red[d] + red[64 + d] + red[128 + d] + red[192 + d];
        float m = s;
        #pragma unroll
        for (int off = 32; off > 0; off >>= 1) m = fmaxf(m, __shfl_xor(m, off));
        const float e = expf(s - m);
        float sum = e;
        #pragma unroll
        for (int off = 32; off > 0; off >>= 1) sum += __shfl_xor(sum, off);
        mbf[(size_t)b * 4096 + c * 64 + d] = bfrne(e / sum + (c == d ? 1.f : 0.f));
    }
}

// ---------------------------------------------------------------------------
// Kernel 3 v9 (global_load_lds staged): out[b,c,n] = sum_d M[c,d]*X[b,d,n]
// x-tile [64d][256n] fp32 staged via 16 wave-level global_load_lds(16B/lane)
// instructions per wave — each 1KB fully coalesced.  Per-lane global chunk
// index pre-swizzled (l^4 for odd d>>3 rows) so the fragment ds_reads land
// 2 lanes/bank (free).  Fragments read as ds_read_b32 + bf16 convert; MFMA
// and store epilogue identical to the validated v6/v8.
// ---------------------------------------------------------------------------
__global__ __launch_bounds__(256, 2) void k3_out(const float* __restrict__ x,
                                                 const unsigned short* __restrict__ mbf,
                                                 float* __restrict__ out) {
    const int nbk = blockIdx.x;
    const int b   = blockIdx.y;
    const int t   = threadIdx.x;
    const int w   = t >> 6;
    const int l   = t & 63;
    const int g   = l >> 4;
    const int col = l & 15;

    __shared__ float Xs[64 * 256];   // [d][n-chunk-swizzled], 64KB

    const int nblk = nbk * 256;
    const float* xb = x + (size_t)b * CHW_;

    // --- stage: wave w loads rows 16w..16w+15, 1KB per instruction ---
    #pragma unroll
    for (int i = 0; i < 16; i++) {
        const int d = 16 * w + i;
        const int p = ((d >> 3) & 1) << 2;               // chunk XOR 0 or 4
        const float* gp = xb + (size_t)d * HW_ + nblk + 4 * (l ^ p);
        __builtin_amdgcn_global_load_lds(
            (const __attribute__((address_space(1))) void*)gp,
            (__attribute__((address_space(3))) void*)(&Xs[d * 256]),
            16, 0, 0);
    }

    // --- A-fragments while staging is in flight (L2-hot) ---
    bf16x8 afr[4][2];
    const unsigned short* mb = mbf + (size_t)b * 4096;
    #pragma unroll
    for (int ct = 0; ct < 4; ct++)
        #pragma unroll
        for (int ks = 0; ks < 2; ks++)
            afr[ct][ks] = *(const bf16x8*)(mb + (16 * ct + col) * 64 + 32 * ks + 8 * g);

    __syncthreads();   // drains vmcnt (global_load_lds) before LDS reads

    f32x4v acc[4][4];   // [ct][nt]
    #pragma unroll
    for (int ct = 0; ct < 4; ct++)
        #pragma unroll
        for (int nt = 0; nt < 4; nt++)
            acc[ct][nt] = (f32x4v)(0.f);

    const int psw = (g & 1) << 2;    // read-side chunk XOR (matches staging)

    #pragma unroll
    for (int nt = 0; nt < 4; nt++) {
        const int n  = 64 * w + 16 * nt + col;
        const int cn = n >> 2;       // 16w + 4nt + (col>>2)
        const int eo = ((cn ^ psw) << 2) + (col & 3);

        bf16x8 bfr[2];
        #pragma unroll
        for (int ks = 0; ks < 2; ks++)
            #pragma unroll
            for (int j = 0; j < 8; j++) {
                const int r = 32 * ks + 8 * g + j;
                bfr[ks][j] = (short)bfrne(Xs[r * 256 + eo]);
            }

        #pragma unroll
        for (int ct = 0; ct < 4; ct++)
            #pragma unroll
            for (int ks = 0; ks < 2; ks++)
                acc[ct][nt] = __builtin_amdgcn_mfma_f32_16x16x32_bf16(
                    afr[ct][ks], bfr[ks], acc[ct][nt], 0, 0, 0);
    }

    // --- store: D[row=16ct+4g+r][col = nblk + 64w + 16nt + col] ---
    float* ob = out + (size_t)b * CHW_;
    #pragma unroll
    for (int ct = 0; ct < 4; ct++)
        #pragma unroll
        for (int nt = 0; nt < 4; nt++)
            #pragma unroll
            for (int r = 0; r < 4; r++)
                ob[(size_t)(16 * ct + 4 * g + r) * HW_ + nblk + 64 * w + 16 * nt + col] =
                    acc[ct][nt][r];
}

// ---------------------------------------------------------------------------
extern "C" void kernel_launch(void* const* d_in, const int* in_sizes, int n_in,
                              void* d_out, int out_size, void* d_ws, size_t ws_size,
                              hipStream_t stream) {
    const float* x = (const float*)d_in[0];
    float* out = (float*)d_out;

    float* wsf          = (float*)d_ws;
    unsigned short* mbf = (unsigned short*)wsf;      // B*4096 ushorts (128KB)
    float* partial      = wsf + (size_t)B_ * 4096;   // B*nch*4096 floats

    int nch = 64;
    while (nch > 1) {
        size_t need = (size_t)B_ * 4096 * sizeof(float)
                    + (size_t)B_ * nch * 4096 * sizeof(float);
        if (need <= ws_size) break;
        nch >>= 1;
    }
    const int nb = HW_ / nch;

    k1_gram<<<dim3(nch, B_), 256, 0, stream>>>(x, partial, nch, nb);
    k2_softmax<<<dim3(C_, B_), 256, 0, stream>>>(partial, mbf, nch);
    k3_out<<<dim3(HW_ / 256, B_), 256, 0, stream>>>(x, mbf, out);
}

// Round 15
// 206.369 us; speedup vs baseline: 1.2290x; 1.0132x over previous
//
#include <hip/hip_runtime.h>

#define B_   16
#define C_   64
#define HW_  65536
#define CHW_ (C_ * HW_)   // 4194304 elements per batch

typedef short bf16x8 __attribute__((ext_vector_type(8)));
typedef float f32x4v __attribute__((ext_vector_type(4)));

// fp32 -> bf16 round-to-nearest-even
__device__ __forceinline__ unsigned short bfrne(float f) {
    unsigned int u = __float_as_uint(f);
    u += 0x7FFFu + ((u >> 16) & 1u);
    return (unsigned short)(u >> 16);
}
__device__ __forceinline__ float bfdec(unsigned short h) {
    return __uint_as_float((unsigned int)h << 16);
}

// ---------------------------------------------------------------------------
// Kernel 1 v7 (split-bf16 MFMA + B via global_load_lds, double-buffered):
// S[b,c,d] = sum_n A[c][n]*B[n][d]; x = hi+lo bf16; S ~= hh+hl+lh.
// Per 32-n step the B tile (32x64 fp32 = 8KB) is contiguous in memory:
// staged wave-privately with 8x global_load_lds (1KB coalesced each),
// ping-pong double-buffer, counted vmcnt(8) keeps the prefetch in flight.
// Chunk swizzle (global chunk c^(4*(r>>3)) -> LDS chunk c) makes fragment
// ds_reads 2 lanes/bank (free); read offset folds to eo = 16*(dt^g)+col.
// Epilogue reduce aliases the staging LDS.
// ---------------------------------------------------------------------------
__global__ __launch_bounds__(256, 2) void k1_gram(const float* __restrict__ x,
                                                  float* __restrict__ partial,
                                                  int nch, int nb) {
    const int ch  = blockIdx.x;
    const int b   = blockIdx.y;
    const int t   = threadIdx.x;
    const int w   = t >> 6;
    const int l   = t & 63;
    const int g   = l >> 4;      // k-octet selector
    const int col = l & 15;      // A-row / B-col within 16-tile

    __shared__ float Bs[4][2][2048];   // [wave][pingpong][32n x 64d], 64KB

    const float* xb = x + (size_t)b * CHW_;
    const int nq  = nb >> 2;     // n per wave
    const int nw0 = ch * nb + w * nq;
    const int nit = nq >> 5;     // 32-n steps per wave

    // wave-private B staging: 8x 1KB coalesced, source chunk pre-swizzled
#define K1_STAGE(dst, ns)                                                  \
    {                                                                      \
        const float* bsrc = xb + (size_t)(ns) * C_;                        \
        _Pragma("unroll")                                                  \
        for (int i = 0; i < 8; i++) {                                      \
            const int sw = (i >> 1) << 2;                                  \
            const float* gp = bsrc + 256 * i + 64 * (l >> 4)               \
                              + 4 * ((l & 15) ^ sw);                       \
            __builtin_amdgcn_global_load_lds(                              \
                (const __attribute__((address_space(1))) void*)gp,         \
                (__attribute__((address_space(3))) void*)((dst) + 256 * i),\
                16, 0, 0);                                                 \
        }                                                                  \
    }

    f32x4v acc[4][4];            // [ct][dt]
    #pragma unroll
    for (int ct = 0; ct < 4; ct++)
        #pragma unroll
        for (int dt = 0; dt < 4; dt++) acc[ct][dt] = (f32x4v)(0.f);

    K1_STAGE(Bs[w][0], nw0);     // prologue

    for (int it = 0; it < nit; ++it) {
        const int ns = nw0 + (it << 5);
        float* cur = Bs[w][it & 1];
        float* nxt = Bs[w][(it + 1) & 1];

        // --- A loads issued first (oldest in vmcnt FIFO) ---
        float av[4][8];
        #pragma unroll
        for (int ct = 0; ct < 4; ct++) {
            const float* ap = xb + (size_t)(16 * ct + col) * HW_ + ns + 8 * g;
            *(float4*)&av[ct][0] = *(const float4*)ap;
            *(float4*)&av[ct][4] = *(const float4*)(ap + 4);
        }

        // --- prefetch next B tile ---
        if (it + 1 < nit) K1_STAGE(nxt, ns + 32);

        // --- convert A while loads/staging fly ---
        bf16x8 ahi[4], alo[4];
        #pragma unroll
        for (int ct = 0; ct < 4; ct++)
            #pragma unroll
            for (int j = 0; j < 8; j++) {
                const unsigned short h = bfrne(av[ct][j]);
                ahi[ct][j] = (short)h;
                alo[ct][j] = (short)bfrne(av[ct][j] - bfdec(h));
            }

        // --- drain cur's staging (leave the 8 prefetch ops in flight) ---
        if (it + 1 < nit) asm volatile("s_waitcnt vmcnt(8)" ::: "memory");
        else              asm volatile("s_waitcnt vmcnt(0)" ::: "memory");

        // --- B fragments from LDS (2 lanes/bank) + 48 MFMAs ---
        #pragma unroll
        for (int dt = 0; dt < 4; dt++) {
            const int eo = 16 * (dt ^ g) + col;
            float bv[8];
            #pragma unroll
            for (int j = 0; j < 8; j++) bv[j] = cur[(8 * g + j) * 64 + eo];
            bf16x8 bhi, blo;
            #pragma unroll
            for (int j = 0; j < 8; j++) {
                const unsigned short h = bfrne(bv[j]);
                bhi[j] = (short)h;
                blo[j] = (short)bfrne(bv[j] - bfdec(h));
            }
            #pragma unroll
            for (int ct = 0; ct < 4; ct++) {
                acc[ct][dt] = __builtin_amdgcn_mfma_f32_16x16x32_bf16(
                    ahi[ct], bhi, acc[ct][dt], 0, 0, 0);
                acc[ct][dt] = __builtin_amdgcn_mfma_f32_16x16x32_bf16(
                    ahi[ct], blo, acc[ct][dt], 0, 0, 0);
                acc[ct][dt] = __builtin_amdgcn_mfma_f32_16x16x32_bf16(
                    alo[ct], bhi, acc[ct][dt], 0, 0, 0);
            }
        }
    }
#undef K1_STAGE

    // --- cross-wave reduce (aliases staging LDS; all staging drained) ---
    float* sred = (float*)Bs;
    for (int wr = 0; wr < 4; wr++) {
        if (w == wr) {
            #pragma unroll
            for (int ct = 0; ct < 4; ct++)
                #pragma unroll
                for (int dt = 0; dt < 4; dt++)
                    #pragma unroll
                    for (int r = 0; r < 4; r++) {
                        const int idx = (16 * ct + 4 * g + r) * 64 + 16 * dt + col;
                        if (wr == 0) sred[idx] = acc[ct][dt][r];
                        else         sred[idx] += acc[ct][dt][r];
                    }
        }
        __syncthreads();
    }

    float* pb = partial + (size_t)(b * nch + ch) * 4096;
    for (int i = 4 * t; i < 4096; i += 1024)
        *(float4*)&pb[i] = *(const float4*)&sred[i];
}

// ---------------------------------------------------------------------------
// Kernel 2 v3: reduce partials + softmax (unchanged).
// Writes mbf[b,c,d] = bf16( softmax(S)[b,c,d] + (c==d) ).
// ---------------------------------------------------------------------------
__global__ __launch_bounds__(256) void k2_softmax(const float* __restrict__ partial,
                                                  unsigned short* __restrict__ mbf,
                                                  int nch) {
    const int c = blockIdx.x;
    const int b = blockIdx.y;
    const int t = threadIdx.x;
    const int w = t >> 6;
    const int d = t & 63;

    float s = 0.f;
    for (int ch = w; ch < nch; ch += 4)
        s += partial[(size_t)(b * nch + ch) * 4096 + c * 64 + d];

    __shared__ float red[256];
    red[t] = s;
    __syncthreads();
    if (w == 0) {
        s = red[d] + red[64 + d] + red[128 + d] + red[192 + d];
        float m = s;
        #pragma unroll
        for (int off = 32; off > 0; off >>= 1) m = fmaxf(m, __shfl_xor(m, off));
        const float e = expf(s - m);
        float sum = e;
        #pragma unroll
        for (int off = 32; off > 0; off >>= 1) sum += __shfl_xor(sum, off);
        mbf[(size_t)b * 4096 + c * 64 + d] = bfrne(e / sum + (c == d ? 1.f : 0.f));
    }
}

// ---------------------------------------------------------------------------
// Kernel 3 v9 (global_load_lds staged — proven R14, unchanged):
// out[b,c,n] = sum_d M[c,d] * X[b, d*HW + n]
// ---------------------------------------------------------------------------
__global__ __launch_bounds__(256, 2) void k3_out(const float* __restrict__ x,
                                                 const unsigned short* __restrict__ mbf,
                                                 float* __restrict__ out) {
    const int nbk = blockIdx.x;
    const int b   = blockIdx.y;
    const int t   = threadIdx.x;
    const int w   = t >> 6;
    const int l   = t & 63;
    const int g   = l >> 4;
    const int col = l & 15;

    __shared__ float Xs[64 * 256];   // [d][n-chunk-swizzled], 64KB

    const int nblk = nbk * 256;
    const float* xb = x + (size_t)b * CHW_;

    #pragma unroll
    for (int i = 0; i < 16; i++) {
        const int d = 16 * w + i;
        const int p = ((d >> 3) & 1) << 2;
        const float* gp = xb + (size_t)d * HW_ + nblk + 4 * (l ^ p);
        __builtin_amdgcn_global_load_lds(
            (const __attribute__((address_space(1))) void*)gp,
            (__attribute__((address_space(3))) void*)(&Xs[d * 256]),
            16, 0, 0);
    }

    bf16x8 afr[4][2];
    const unsigned short* mb = mbf + (size_t)b * 4096;
    #pragma unroll
    for (int ct = 0; ct < 4; ct++)
        #pragma unroll
        for (int ks = 0; ks < 2; ks++)
            afr[ct][ks] = *(const bf16x8*)(mb + (16 * ct + col) * 64 + 32 * ks + 8 * g);

    __syncthreads();

    f32x4v acc[4][4];
    #pragma unroll
    for (int ct = 0; ct < 4; ct++)
        #pragma unroll
        for (int nt = 0; nt < 4; nt++)
            acc[ct][nt] = (f32x4v)(0.f);

    const int psw = (g & 1) << 2;

    #pragma unroll
    for (int nt = 0; nt < 4; nt++) {
        const int n  = 64 * w + 16 * nt + col;
        const int cn = n >> 2;
        const int eo = ((cn ^ psw) << 2) + (col & 3);

        bf16x8 bfr[2];
        #pragma unroll
        for (int ks = 0; ks < 2; ks++)
            #pragma unroll
            for (int j = 0; j < 8; j++) {
                const int r = 32 * ks + 8 * g + j;
                bfr[ks][j] = (short)bfrne(Xs[r * 256 + eo]);
            }

        #pragma unroll
        for (int ct = 0; ct < 4; ct++)
            #pragma unroll
            for (int ks = 0; ks < 2; ks++)
                acc[ct][nt] = __builtin_amdgcn_mfma_f32_16x16x32_bf16(
                    afr[ct][ks], bfr[ks], acc[ct][nt], 0, 0, 0);
    }

    float* ob = out + (size_t)b * CHW_;
    #pragma unroll
    for (int ct = 0; ct < 4; ct++)
        #pragma unroll
        for (int nt = 0; nt < 4; nt++)
            #pragma unroll
            for (int r = 0; r < 4; r++)
                ob[(size_t)(16 * ct + 4 * g + r) * HW_ + nblk + 64 * w + 16 * nt + col] =
                    acc[ct][nt][r];
}

// ---------------------------------------------------------------------------
extern "C" void kernel_launch(void* const* d_in, const int* in_sizes, int n_in,
                              void* d_out, int out_size, void* d_ws, size_t ws_size,
                              hipStream_t stream) {
    const float* x = (const float*)d_in[0];
    float* out = (float*)d_out;

    float* wsf          = (float*)d_ws;
    unsigned short* mbf = (unsigned short*)wsf;      // B*4096 ushorts (128KB)
    float* partial      = wsf + (size_t)B_ * 4096;   // B*nch*4096 floats

    int nch = 64;
    while (nch > 1) {
        size_t need = (size_t)B_ * 4096 * sizeof(float)
                    + (size_t)B_ * nch * 4096 * sizeof(float);
        if (need <= ws_size) break;
        nch >>= 1;
    }
    const int nb = HW_ / nch;

    k1_gram<<<dim3(nch, B_), 256, 0, stream>>>(x, partial, nch, nb);
    k2_softmax<<<dim3(C_, B_), 256, 0, stream>>>(partial, mbf, nch);
    k3_out<<<dim3(HW_ / 256, B_), 256, 0, stream>>>(x, mbf, out);
}

// Round 16
// 198.683 us; speedup vs baseline: 1.2766x; 1.0387x over previous
//
#include <hip/hip_runtime.h>

#define B_   16
#define C_   64
#define HW_  65536
#define CHW_ (C_ * HW_)   // 4194304 elements per batch
#define XSTRIDE 260       // LDS row stride: 260*4B = 1040 ≡ 0 mod 16 (b128-aligned)

typedef short bf16x8 __attribute__((ext_vector_type(8)));
typedef float f32x4v __attribute__((ext_vector_type(4)));

// fp32 -> bf16 round-to-nearest-even
__device__ __forceinline__ unsigned short bfrne(float f) {
    unsigned int u = __float_as_uint(f);
    u += 0x7FFFu + ((u >> 16) & 1u);
    return (unsigned short)(u >> 16);
}
__device__ __forceinline__ float bfdec(unsigned short h) {
    return __uint_as_float((unsigned int)h << 16);
}

// ---------------------------------------------------------------------------
// Kernel 1 v7 (unchanged from R15 — 92us): split-bf16 MFMA + B staged via
// global_load_lds, double-buffered, counted vmcnt.
// ---------------------------------------------------------------------------
__global__ __launch_bounds__(256, 2) void k1_gram(const float* __restrict__ x,
                                                  float* __restrict__ partial,
                                                  int nch, int nb) {
    const int ch  = blockIdx.x;
    const int b   = blockIdx.y;
    const int t   = threadIdx.x;
    const int w   = t >> 6;
    const int l   = t & 63;
    const int g   = l >> 4;
    const int col = l & 15;

    __shared__ float Bs[4][2][2048];   // [wave][pingpong][32n x 64d], 64KB

    const float* xb = x + (size_t)b * CHW_;
    const int nq  = nb >> 2;
    const int nw0 = ch * nb + w * nq;
    const int nit = nq >> 5;

#define K1_STAGE(dst, ns)                                                  \
    {                                                                      \
        const float* bsrc = xb + (size_t)(ns) * C_;                        \
        _Pragma("unroll")                                                  \
        for (int i = 0; i < 8; i++) {                                      \
            const int sw = (i >> 1) << 2;                                  \
            const float* gp = bsrc + 256 * i + 64 * (l >> 4)               \
                              + 4 * ((l & 15) ^ sw);                       \
            __builtin_amdgcn_global_load_lds(                              \
                (const __attribute__((address_space(1))) void*)gp,         \
                (__attribute__((address_space(3))) void*)((dst) + 256 * i),\
                16, 0, 0);                                                 \
        }                                                                  \
    }

    f32x4v acc[4][4];
    #pragma unroll
    for (int ct = 0; ct < 4; ct++)
        #pragma unroll
        for (int dt = 0; dt < 4; dt++) acc[ct][dt] = (f32x4v)(0.f);

    K1_STAGE(Bs[w][0], nw0);

    for (int it = 0; it < nit; ++it) {
        const int ns = nw0 + (it << 5);
        float* cur = Bs[w][it & 1];
        float* nxt = Bs[w][(it + 1) & 1];

        float av[4][8];
        #pragma unroll
        for (int ct = 0; ct < 4; ct++) {
            const float* ap = xb + (size_t)(16 * ct + col) * HW_ + ns + 8 * g;
            *(float4*)&av[ct][0] = *(const float4*)ap;
            *(float4*)&av[ct][4] = *(const float4*)(ap + 4);
        }

        if (it + 1 < nit) K1_STAGE(nxt, ns + 32);

        bf16x8 ahi[4], alo[4];
        #pragma unroll
        for (int ct = 0; ct < 4; ct++)
            #pragma unroll
            for (int j = 0; j < 8; j++) {
                const unsigned short h = bfrne(av[ct][j]);
                ahi[ct][j] = (short)h;
                alo[ct][j] = (short)bfrne(av[ct][j] - bfdec(h));
            }

        if (it + 1 < nit) asm volatile("s_waitcnt vmcnt(8)" ::: "memory");
        else              asm volatile("s_waitcnt vmcnt(0)" ::: "memory");

        #pragma unroll
        for (int dt = 0; dt < 4; dt++) {
            const int eo = 16 * (dt ^ g) + col;
            float bv[8];
            #pragma unroll
            for (int j = 0; j < 8; j++) bv[j] = cur[(8 * g + j) * 64 + eo];
            bf16x8 bhi, blo;
            #pragma unroll
            for (int j = 0; j < 8; j++) {
                const unsigned short h = bfrne(bv[j]);
                bhi[j] = (short)h;
                blo[j] = (short)bfrne(bv[j] - bfdec(h));
            }
            #pragma unroll
            for (int ct = 0; ct < 4; ct++) {
                acc[ct][dt] = __builtin_amdgcn_mfma_f32_16x16x32_bf16(
                    ahi[ct], bhi, acc[ct][dt], 0, 0, 0);
                acc[ct][dt] = __builtin_amdgcn_mfma_f32_16x16x32_bf16(
                    ahi[ct], blo, acc[ct][dt], 0, 0, 0);
                acc[ct][dt] = __builtin_amdgcn_mfma_f32_16x16x32_bf16(
                    alo[ct], bhi, acc[ct][dt], 0, 0, 0);
            }
        }
    }
#undef K1_STAGE

    float* sred = (float*)Bs;
    for (int wr = 0; wr < 4; wr++) {
        if (w == wr) {
            #pragma unroll
            for (int ct = 0; ct < 4; ct++)
                #pragma unroll
                for (int dt = 0; dt < 4; dt++)
                    #pragma unroll
                    for (int r = 0; r < 4; r++) {
                        const int idx = (16 * ct + 4 * g + r) * 64 + 16 * dt + col;
                        if (wr == 0) sred[idx] = acc[ct][dt][r];
                        else         sred[idx] += acc[ct][dt][r];
                    }
        }
        __syncthreads();
    }

    float* pb = partial + (size_t)(b * nch + ch) * 4096;
    for (int i = 4 * t; i < 4096; i += 1024)
        *(float4*)&pb[i] = *(const float4*)&sred[i];
}

// ---------------------------------------------------------------------------
// Kernel 2 v3: reduce partials + softmax (unchanged).
// ---------------------------------------------------------------------------
__global__ __launch_bounds__(256) void k2_softmax(const float* __restrict__ partial,
                                                  unsigned short* __restrict__ mbf,
                                                  int nch) {
    const int c = blockIdx.x;
    const int b = blockIdx.y;
    const int t = threadIdx.x;
    const int w = t >> 6;
    const int d = t & 63;

    float s = 0.f;
    for (int ch = w; ch < nch; ch += 4)
        s += partial[(size_t)(b * nch + ch) * 4096 + c * 64 + d];

    __shared__ float red[256];
    red[t] = s;
    __syncthreads();
    if (w == 0) {
        s = red[d] + red[64 + d] + red[128 + d] + red[192 + d];
        float m = s;
        #pragma unroll
        for (int off = 32; off > 0; off >>= 1) m = fmaxf(m, __shfl_xor(m, off));
        const float e = expf(s - m);
        float sum = e;
        #pragma unroll
        for (int off = 32; off > 0; off >>= 1) sum += __shfl_xor(sum, off);
        mbf[(size_t)b * 4096 + c * 64 + d] = bfrne(e / sum + (c == d ? 1.f : 0.f));
    }
}

// ---------------------------------------------------------------------------
// Kernel 3 v10 (v9 + LDS-transpose coalesced stores):
// out[b,c,n] = sum_d M[c,d] * X[b, d*HW + n]
// Staging/MFMA identical to v9 (stride 260).  Epilogue: acc -> LDS
// (banks 2/lane, free) -> 1KB-contiguous float4 stores (16 instr/wave,
// replaces 64 scattered 4x64B scalar stores).
// ---------------------------------------------------------------------------
__global__ __launch_bounds__(256, 2) void k3_out(const float* __restrict__ x,
                                                 const unsigned short* __restrict__ mbf,
                                                 float* __restrict__ out) {
    const int nbk = blockIdx.x;
    const int b   = blockIdx.y;
    const int t   = threadIdx.x;
    const int w   = t >> 6;
    const int l   = t & 63;
    const int g   = l >> 4;
    const int col = l & 15;

    __shared__ float Xs[64 * XSTRIDE];   // 66.5KB; staging then store-transpose

    const int nblk = nbk * 256;
    const float* xb = x + (size_t)b * CHW_;

    // --- stage: wave w loads rows 16w..16w+15, 1KB per instruction ---
    #pragma unroll
    for (int i = 0; i < 16; i++) {
        const int d = 16 * w + i;
        const int p = ((d >> 3) & 1) << 2;
        const float* gp = xb + (size_t)d * HW_ + nblk + 4 * (l ^ p);
        __builtin_amdgcn_global_load_lds(
            (const __attribute__((address_space(1))) void*)gp,
            (__attribute__((address_space(3))) void*)(&Xs[d * XSTRIDE]),
            16, 0, 0);
    }

    bf16x8 afr[4][2];
    const unsigned short* mb = mbf + (size_t)b * 4096;
    #pragma unroll
    for (int ct = 0; ct < 4; ct++)
        #pragma unroll
        for (int ks = 0; ks < 2; ks++)
            afr[ct][ks] = *(const bf16x8*)(mb + (16 * ct + col) * 64 + 32 * ks + 8 * g);

    __syncthreads();   // staging drained (vmcnt) before LDS reads

    f32x4v acc[4][4];
    #pragma unroll
    for (int ct = 0; ct < 4; ct++)
        #pragma unroll
        for (int nt = 0; nt < 4; nt++)
            acc[ct][nt] = (f32x4v)(0.f);

    const int psw = (g & 1) << 2;

    #pragma unroll
    for (int nt = 0; nt < 4; nt++) {
        const int n  = 64 * w + 16 * nt + col;
        const int cn = n >> 2;
        const int eo = ((cn ^ psw) << 2) + (col & 3);

        bf16x8 bfr[2];
        #pragma unroll
        for (int ks = 0; ks < 2; ks++)
            #pragma unroll
            for (int j = 0; j < 8; j++) {
                const int r = 32 * ks + 8 * g + j;
                bfr[ks][j] = (short)bfrne(Xs[r * XSTRIDE + eo]);
            }

        #pragma unroll
        for (int ct = 0; ct < 4; ct++)
            #pragma unroll
            for (int ks = 0; ks < 2; ks++)
                acc[ct][nt] = __builtin_amdgcn_mfma_f32_16x16x32_bf16(
                    afr[ct][ks], bfr[ks], acc[ct][nt], 0, 0, 0);
    }

    // --- transpose through LDS for coalesced stores ---
    __syncthreads();   // all Xs reads done; safe to overwrite
    #pragma unroll
    for (int ct = 0; ct < 4; ct++)
        #pragma unroll
        for (int nt = 0; nt < 4; nt++)
            #pragma unroll
            for (int r = 0; r < 4; r++)
                Xs[(16 * ct + 4 * g + r) * XSTRIDE + 64 * w + 16 * nt + col] =
                    acc[ct][nt][r];
    __syncthreads();

    // --- store: wave w writes rows 16w..16w+15, 1KB contiguous each ---
    float* ob = out + (size_t)b * CHW_ + nblk;
    #pragma unroll
    for (int i = 0; i < 16; i++) {
        const int row = 16 * w + i;
        const float4 v = *(const float4*)&Xs[row * XSTRIDE + 4 * l];
        *(float4*)(ob + (size_t)row * HW_ + 4 * l) = v;
    }
}

// ---------------------------------------------------------------------------
extern "C" void kernel_launch(void* const* d_in, const int* in_sizes, int n_in,
                              void* d_out, int out_size, void* d_ws, size_t ws_size,
                              hipStream_t stream) {
    const float* x = (const float*)d_in[0];
    float* out = (float*)d_out;

    float* wsf          = (float*)d_ws;
    unsigned short* mbf = (unsigned short*)wsf;      // B*4096 ushorts (128KB)
    float* partial      = wsf + (size_t)B_ * 4096;   // B*nch*4096 floats

    int nch = 64;
    while (nch > 1) {
        size_t need = (size_t)B_ * 4096 * sizeof(float)
                    + (size_t)B_ * nch * 4096 * sizeof(float);
        if (need <= ws_size) break;
        nch >>= 1;
    }
    const int nb = HW_ / nch;

    k1_gram<<<dim3(nch, B_), 256, 0, stream>>>(x, partial, nch, nb);
    k2_softmax<<<dim3(C_, B_), 256, 0, stream>>>(partial, mbf, nch);
    k3_out<<<dim3(HW_ / 256, B_), 256, 0, stream>>>(x, mbf, out);
}

// Round 17
// 195.922 us; speedup vs baseline: 1.2945x; 1.0141x over previous
//
#include <hip/hip_runtime.h>

#define B_   16
#define C_   64
#define HW_  65536
#define CHW_ (C_ * HW_)   // 4194304 elements per batch
#define XSTRIDE 260       // k3 LDS row stride: 1040B ≡ 0 mod 16 (b128-aligned)

typedef short bf16x8 __attribute__((ext_vector_type(8)));
typedef float f32x4v __attribute__((ext_vector_type(4)));

// fp32 -> bf16 round-to-nearest-even
__device__ __forceinline__ unsigned short bfrne(float f) {
    unsigned int u = __float_as_uint(f);
    u += 0x7FFFu + ((u >> 16) & 1u);
    return (unsigned short)(u >> 16);
}
__device__ __forceinline__ float bfdec(unsigned short h) {
    return __uint_as_float((unsigned int)h << 16);
}

// ---------------------------------------------------------------------------
// Kernel 1 v8 (v7 + A register double-buffer): split-bf16 MFMA;
// S[b,c,d] = sum_n A[c][n]*B[n][d]; S ~= hh+hl+lh.
// B staged via global_load_lds (8x 1KB, wave-private, ping-pong LDS).
// A now ping-pongs through REGISTERS (avA/avB, static unroll-2): iteration i
// converts A_i loaded a full iteration earlier — no per-iter A-load stall.
// Steady state: 32 VMEM outstanding; vmcnt(16) leaves the 2 prefetch groups.
// ---------------------------------------------------------------------------
__global__ __launch_bounds__(256, 2) void k1_gram(const float* __restrict__ x,
                                                  float* __restrict__ partial,
                                                  int nch, int nb) {
    const int ch  = blockIdx.x;
    const int b   = blockIdx.y;
    const int t   = threadIdx.x;
    const int w   = t >> 6;
    const int l   = t & 63;
    const int g   = l >> 4;
    const int col = l & 15;

    __shared__ float Bs[4][2][2048];   // [wave][pingpong][32n x 64d], 64KB

    const float* xb = x + (size_t)b * CHW_;
    const int nq  = nb >> 2;
    const int nw0 = ch * nb + w * nq;
    const int nit = nq >> 5;           // 32-n steps per wave (8 at nch=64; even)

#define K1_STAGE(dst, ns)                                                  \
    {                                                                      \
        const float* bsrc = xb + (size_t)(ns) * C_;                        \
        _Pragma("unroll")                                                  \
        for (int i = 0; i < 8; i++) {                                      \
            const int sw = (i >> 1) << 2;                                  \
            const float* gp = bsrc + 256 * i + 64 * (l >> 4)               \
                              + 4 * ((l & 15) ^ sw);                       \
            __builtin_amdgcn_global_load_lds(                              \
                (const __attribute__((address_space(1))) void*)gp,         \
                (__attribute__((address_space(3))) void*)((dst) + 256 * i),\
                16, 0, 0);                                                 \
        }                                                                  \
    }

#define K1_LOADA(AV, ns)                                                   \
    _Pragma("unroll")                                                      \
    for (int ct = 0; ct < 4; ct++) {                                       \
        const float* ap = xb + (size_t)(16 * ct + col) * HW_ + (ns) + 8 * g; \
        *(float4*)&AV[ct][0] = *(const float4*)ap;                         \
        *(float4*)&AV[ct][4] = *(const float4*)(ap + 4);                   \
    }

#define K1_CONVA(AV)                                                       \
    _Pragma("unroll")                                                      \
    for (int ct = 0; ct < 4; ct++)                                         \
        _Pragma("unroll")                                                  \
        for (int j = 0; j < 8; j++) {                                      \
            const unsigned short h = bfrne(AV[ct][j]);                     \
            ahi[ct][j] = (short)h;                                         \
            alo[ct][j] = (short)bfrne(AV[ct][j] - bfdec(h));               \
        }

#define K1_BPHASE(cur)                                                     \
    _Pragma("unroll")                                                      \
    for (int dt = 0; dt < 4; dt++) {                                       \
        const int eo = 16 * (dt ^ g) + col;                                \
        float bv[8];                                                       \
        _Pragma("unroll")                                                  \
        for (int j = 0; j < 8; j++) bv[j] = (cur)[(8 * g + j) * 64 + eo];  \
        bf16x8 bhi, blo;                                                   \
        _Pragma("unroll")                                                  \
        for (int j = 0; j < 8; j++) {                                      \
            const unsigned short h = bfrne(bv[j]);                         \
            bhi[j] = (short)h;                                             \
            blo[j] = (short)bfrne(bv[j] - bfdec(h));                       \
        }                                                                  \
        _Pragma("unroll")                                                  \
        for (int ct = 0; ct < 4; ct++) {                                   \
            acc[ct][dt] = __builtin_amdgcn_mfma_f32_16x16x32_bf16(         \
                ahi[ct], bhi, acc[ct][dt], 0, 0, 0);                       \
            acc[ct][dt] = __builtin_amdgcn_mfma_f32_16x16x32_bf16(         \
                ahi[ct], blo, acc[ct][dt], 0, 0, 0);                       \
            acc[ct][dt] = __builtin_amdgcn_mfma_f32_16x16x32_bf16(         \
                alo[ct], bhi, acc[ct][dt], 0, 0, 0);                       \
        }                                                                  \
    }

    f32x4v acc[4][4];
    #pragma unroll
    for (int ct = 0; ct < 4; ct++)
        #pragma unroll
        for (int dt = 0; dt < 4; dt++) acc[ct][dt] = (f32x4v)(0.f);

    float avA[4][8], avB[4][8];
    bf16x8 ahi[4], alo[4];

    K1_STAGE(Bs[w][0], nw0);
    K1_LOADA(avA, nw0);

    for (int it2 = 0; it2 < nit; it2 += 2) {
        // --- tile it2 (even): consume avA + Bs[w][0]; prefetch it2+1 ---
        {
            const int ns = nw0 + (it2 << 5);
            K1_LOADA(avB, ns + 32);            // it2+1 < nit always (nit even)
            K1_STAGE(Bs[w][1], ns + 32);
            K1_CONVA(avA);
            asm volatile("s_waitcnt vmcnt(16)" ::: "memory");
            K1_BPHASE(Bs[w][0]);
        }
        // --- tile it2+1 (odd): consume avB + Bs[w][1]; prefetch it2+2 ---
        {
            const int ns = nw0 + ((it2 + 1) << 5);
            if (it2 + 2 < nit) {
                K1_LOADA(avA, ns + 32);
                K1_STAGE(Bs[w][0], ns + 32);
            }
            K1_CONVA(avB);
            if (it2 + 2 < nit) asm volatile("s_waitcnt vmcnt(16)" ::: "memory");
            else               asm volatile("s_waitcnt vmcnt(0)"  ::: "memory");
            K1_BPHASE(Bs[w][1]);
        }
    }
#undef K1_STAGE
#undef K1_LOADA
#undef K1_CONVA
#undef K1_BPHASE

    // --- cross-wave reduce (aliases staging LDS; all staging drained) ---
    float* sred = (float*)Bs;
    for (int wr = 0; wr < 4; wr++) {
        if (w == wr) {
            #pragma unroll
            for (int ct = 0; ct < 4; ct++)
                #pragma unroll
                for (int dt = 0; dt < 4; dt++)
                    #pragma unroll
                    for (int r = 0; r < 4; r++) {
                        const int idx = (16 * ct + 4 * g + r) * 64 + 16 * dt + col;
                        if (wr == 0) sred[idx] = acc[ct][dt][r];
                        else         sred[idx] += acc[ct][dt][r];
                    }
        }
        __syncthreads();
    }

    float* pb = partial + (size_t)(b * nch + ch) * 4096;
    for (int i = 4 * t; i < 4096; i += 1024)
        *(float4*)&pb[i] = *(const float4*)&sred[i];
}

// ---------------------------------------------------------------------------
// Kernel 2 v3: reduce partials + softmax (unchanged).
// ---------------------------------------------------------------------------
__global__ __launch_bounds__(256) void k2_softmax(const float* __restrict__ partial,
                                                  unsigned short* __restrict__ mbf,
                                                  int nch) {
    const int c = blockIdx.x;
    const int b = blockIdx.y;
    const int t = threadIdx.x;
    const int w = t >> 6;
    const int d = t & 63;

    float s = 0.f;
    for (int ch = w; ch < nch; ch += 4)
        s += partial[(size_t)(b * nch + ch) * 4096 + c * 64 + d];

    __shared__ float red[256];
    red[t] = s;
    __syncthreads();
    if (w == 0) {
        s = red[d] + red[64 + d] + red[128 + d] + red[192 + d];
        float m = s;
        #pragma unroll
        for (int off = 32; off > 0; off >>= 1) m = fmaxf(m, __shfl_xor(m, off));
        const float e = expf(s - m);
        float sum = e;
        #pragma unroll
        for (int off = 32; off > 0; off >>= 1) sum += __shfl_xor(sum, off);
        mbf[(size_t)b * 4096 + c * 64 + d] = bfrne(e / sum + (c == d ? 1.f : 0.f));
    }
}

// ---------------------------------------------------------------------------
// Kernel 3 v10 (unchanged from R16 — 82us): global_load_lds staged MFMA +
// LDS-transpose coalesced stores.
// ---------------------------------------------------------------------------
__global__ __launch_bounds__(256, 2) void k3_out(const float* __restrict__ x,
                                                 const unsigned short* __restrict__ mbf,
                                                 float* __restrict__ out) {
    const int nbk = blockIdx.x;
    const int b   = blockIdx.y;
    const int t   = threadIdx.x;
    const int w   = t >> 6;
    const int l   = t & 63;
    const int g   = l >> 4;
    const int col = l & 15;

    __shared__ float Xs[64 * XSTRIDE];   // 66.5KB; staging then store-transpose

    const int nblk = nbk * 256;
    const float* xb = x + (size_t)b * CHW_;

    #pragma unroll
    for (int i = 0; i < 16; i++) {
        const int d = 16 * w + i;
        const int p = ((d >> 3) & 1) << 2;
        const float* gp = xb + (size_t)d * HW_ + nblk + 4 * (l ^ p);
        __builtin_amdgcn_global_load_lds(
            (const __attribute__((address_space(1))) void*)gp,
            (__attribute__((address_space(3))) void*)(&Xs[d * XSTRIDE]),
            16, 0, 0);
    }

    bf16x8 afr[4][2];
    const unsigned short* mb = mbf + (size_t)b * 4096;
    #pragma unroll
    for (int ct = 0; ct < 4; ct++)
        #pragma unroll
        for (int ks = 0; ks < 2; ks++)
            afr[ct][ks] = *(const bf16x8*)(mb + (16 * ct + col) * 64 + 32 * ks + 8 * g);

    __syncthreads();

    f32x4v acc[4][4];
    #pragma unroll
    for (int ct = 0; ct < 4; ct++)
        #pragma unroll
        for (int nt = 0; nt < 4; nt++)
            acc[ct][nt] = (f32x4v)(0.f);

    const int psw = (g & 1) << 2;

    #pragma unroll
    for (int nt = 0; nt < 4; nt++) {
        const int n  = 64 * w + 16 * nt + col;
        const int cn = n >> 2;
        const int eo = ((cn ^ psw) << 2) + (col & 3);

        bf16x8 bfr[2];
        #pragma unroll
        for (int ks = 0; ks < 2; ks++)
            #pragma unroll
            for (int j = 0; j < 8; j++) {
                const int r = 32 * ks + 8 * g + j;
                bfr[ks][j] = (short)bfrne(Xs[r * XSTRIDE + eo]);
            }

        #pragma unroll
        for (int ct = 0; ct < 4; ct++)
            #pragma unroll
            for (int ks = 0; ks < 2; ks++)
                acc[ct][nt] = __builtin_amdgcn_mfma_f32_16x16x32_bf16(
                    afr[ct][ks], bfr[ks], acc[ct][nt], 0, 0, 0);
    }

    __syncthreads();
    #pragma unroll
    for (int ct = 0; ct < 4; ct++)
        #pragma unroll
        for (int nt = 0; nt < 4; nt++)
            #pragma unroll
            for (int r = 0; r < 4; r++)
                Xs[(16 * ct + 4 * g + r) * XSTRIDE + 64 * w + 16 * nt + col] =
                    acc[ct][nt][r];
    __syncthreads();

    float* ob = out + (size_t)b * CHW_ + nblk;
    #pragma unroll
    for (int i = 0; i < 16; i++) {
        const int row = 16 * w + i;
        const float4 v = *(const float4*)&Xs[row * XSTRIDE + 4 * l];
        *(float4*)(ob + (size_t)row * HW_ + 4 * l) = v;
    }
}

// ---------------------------------------------------------------------------
extern "C" void kernel_launch(void* const* d_in, const int* in_sizes, int n_in,
                              void* d_out, int out_size, void* d_ws, size_t ws_size,
                              hipStream_t stream) {
    const float* x = (const float*)d_in[0];
    float* out = (float*)d_out;

    float* wsf          = (float*)d_ws;
    unsigned short* mbf = (unsigned short*)wsf;      // B*4096 ushorts (128KB)
    float* partial      = wsf + (size_t)B_ * 4096;   // B*nch*4096 floats

    int nch = 64;
    while (nch > 1) {
        size_t need = (size_t)B_ * 4096 * sizeof(float)
                    + (size_t)B_ * nch * 4096 * sizeof(float);
        if (need <= ws_size) break;
        nch >>= 1;
    }
    const int nb = HW_ / nch;

    k1_gram<<<dim3(nch, B_), 256, 0, stream>>>(x, partial, nch, nb);
    k2_softmax<<<dim3(C_, B_), 256, 0, stream>>>(partial, mbf, nch);
    k3_out<<<dim3(HW_ / 256, B_), 256, 0, stream>>>(x, mbf, out);
}

// Round 18
// 193.841 us; speedup vs baseline: 1.3084x; 1.0107x over previous
//
#include <hip/hip_runtime.h>

#define B_   16
#define C_   64
#define HW_  65536
#define CHW_ (C_ * HW_)   // 4194304 elements per batch
#define XSTRIDE 260       // k3 LDS row stride: 1040B ≡ 0 mod 16 (b128-aligned)

typedef short bf16x8 __attribute__((ext_vector_type(8)));
typedef float f32x4v __attribute__((ext_vector_type(4)));

// fp32 -> bf16 round-to-nearest-even
__device__ __forceinline__ unsigned short bfrne(float f) {
    unsigned int u = __float_as_uint(f);
    u += 0x7FFFu + ((u >> 16) & 1u);
    return (unsigned short)(u >> 16);
}
__device__ __forceinline__ float bfdec(unsigned short h) {
    return __uint_as_float((unsigned int)h << 16);
}

// ---------------------------------------------------------------------------
// Kernel 1 v8 (unchanged from R17 — ~89us): split-bf16 MFMA; B staged via
// global_load_lds (ping-pong LDS), A ping-pongs through registers.
// ---------------------------------------------------------------------------
__global__ __launch_bounds__(256, 2) void k1_gram(const float* __restrict__ x,
                                                  float* __restrict__ partial,
                                                  int nch, int nb) {
    const int ch  = blockIdx.x;
    const int b   = blockIdx.y;
    const int t   = threadIdx.x;
    const int w   = t >> 6;
    const int l   = t & 63;
    const int g   = l >> 4;
    const int col = l & 15;

    __shared__ float Bs[4][2][2048];   // [wave][pingpong][32n x 64d], 64KB

    const float* xb = x + (size_t)b * CHW_;
    const int nq  = nb >> 2;
    const int nw0 = ch * nb + w * nq;
    const int nit = nq >> 5;

#define K1_STAGE(dst, ns)                                                  \
    {                                                                      \
        const float* bsrc = xb + (size_t)(ns) * C_;                        \
        _Pragma("unroll")                                                  \
        for (int i = 0; i < 8; i++) {                                      \
            const int sw = (i >> 1) << 2;                                  \
            const float* gp = bsrc + 256 * i + 64 * (l >> 4)               \
                              + 4 * ((l & 15) ^ sw);                       \
            __builtin_amdgcn_global_load_lds(                              \
                (const __attribute__((address_space(1))) void*)gp,         \
                (__attribute__((address_space(3))) void*)((dst) + 256 * i),\
                16, 0, 0);                                                 \
        }                                                                  \
    }

#define K1_LOADA(AV, ns)                                                   \
    _Pragma("unroll")                                                      \
    for (int ct = 0; ct < 4; ct++) {                                       \
        const float* ap = xb + (size_t)(16 * ct + col) * HW_ + (ns) + 8 * g; \
        *(float4*)&AV[ct][0] = *(const float4*)ap;                         \
        *(float4*)&AV[ct][4] = *(const float4*)(ap + 4);                   \
    }

#define K1_CONVA(AV)                                                       \
    _Pragma("unroll")                                                      \
    for (int ct = 0; ct < 4; ct++)                                         \
        _Pragma("unroll")                                                  \
        for (int j = 0; j < 8; j++) {                                      \
            const unsigned short h = bfrne(AV[ct][j]);                     \
            ahi[ct][j] = (short)h;                                         \
            alo[ct][j] = (short)bfrne(AV[ct][j] - bfdec(h));               \
        }

#define K1_BPHASE(cur)                                                     \
    _Pragma("unroll")                                                      \
    for (int dt = 0; dt < 4; dt++) {                                       \
        const int eo = 16 * (dt ^ g) + col;                                \
        float bv[8];                                                       \
        _Pragma("unroll")                                                  \
        for (int j = 0; j < 8; j++) bv[j] = (cur)[(8 * g + j) * 64 + eo];  \
        bf16x8 bhi, blo;                                                   \
        _Pragma("unroll")                                                  \
        for (int j = 0; j < 8; j++) {                                      \
            const unsigned short h = bfrne(bv[j]);                         \
            bhi[j] = (short)h;                                             \
            blo[j] = (short)bfrne(bv[j] - bfdec(h));                       \
        }                                                                  \
        _Pragma("unroll")                                                  \
        for (int ct = 0; ct < 4; ct++) {                                   \
            acc[ct][dt] = __builtin_amdgcn_mfma_f32_16x16x32_bf16(         \
                ahi[ct], bhi, acc[ct][dt], 0, 0, 0);                       \
            acc[ct][dt] = __builtin_amdgcn_mfma_f32_16x16x32_bf16(         \
                ahi[ct], blo, acc[ct][dt], 0, 0, 0);                       \
            acc[ct][dt] = __builtin_amdgcn_mfma_f32_16x16x32_bf16(         \
                alo[ct], bhi, acc[ct][dt], 0, 0, 0);                       \
        }                                                                  \
    }

    f32x4v acc[4][4];
    #pragma unroll
    for (int ct = 0; ct < 4; ct++)
        #pragma unroll
        for (int dt = 0; dt < 4; dt++) acc[ct][dt] = (f32x4v)(0.f);

    float avA[4][8], avB[4][8];
    bf16x8 ahi[4], alo[4];

    K1_STAGE(Bs[w][0], nw0);
    K1_LOADA(avA, nw0);

    for (int it2 = 0; it2 < nit; it2 += 2) {
        {
            const int ns = nw0 + (it2 << 5);
            K1_LOADA(avB, ns + 32);
            K1_STAGE(Bs[w][1], ns + 32);
            K1_CONVA(avA);
            asm volatile("s_waitcnt vmcnt(16)" ::: "memory");
            K1_BPHASE(Bs[w][0]);
        }
        {
            const int ns = nw0 + ((it2 + 1) << 5);
            if (it2 + 2 < nit) {
                K1_LOADA(avA, ns + 32);
                K1_STAGE(Bs[w][0], ns + 32);
            }
            K1_CONVA(avB);
            if (it2 + 2 < nit) asm volatile("s_waitcnt vmcnt(16)" ::: "memory");
            else               asm volatile("s_waitcnt vmcnt(0)"  ::: "memory");
            K1_BPHASE(Bs[w][1]);
        }
    }
#undef K1_STAGE
#undef K1_LOADA
#undef K1_CONVA
#undef K1_BPHASE

    float* sred = (float*)Bs;
    for (int wr = 0; wr < 4; wr++) {
        if (w == wr) {
            #pragma unroll
            for (int ct = 0; ct < 4; ct++)
                #pragma unroll
                for (int dt = 0; dt < 4; dt++)
                    #pragma unroll
                    for (int r = 0; r < 4; r++) {
                        const int idx = (16 * ct + 4 * g + r) * 64 + 16 * dt + col;
                        if (wr == 0) sred[idx] = acc[ct][dt][r];
                        else         sred[idx] += acc[ct][dt][r];
                    }
        }
        __syncthreads();
    }

    float* pb = partial + (size_t)(b * nch + ch) * 4096;
    for (int i = 4 * t; i < 4096; i += 1024)
        *(float4*)&pb[i] = *(const float4*)&sred[i];
}

// ---------------------------------------------------------------------------
// Kernel 2 v3: reduce partials + softmax (unchanged).
// ---------------------------------------------------------------------------
__global__ __launch_bounds__(256) void k2_softmax(const float* __restrict__ partial,
                                                  unsigned short* __restrict__ mbf,
                                                  int nch) {
    const int c = blockIdx.x;
    const int b = blockIdx.y;
    const int t = threadIdx.x;
    const int w = t >> 6;
    const int d = t & 63;

    float s = 0.f;
    for (int ch = w; ch < nch; ch += 4)
        s += partial[(size_t)(b * nch + ch) * 4096 + c * 64 + d];

    __shared__ float red[256];
    red[t] = s;
    __syncthreads();
    if (w == 0) {
        s = red[d] + red[64 + d] + red[128 + d] + red[192 + d];
        float m = s;
        #pragma unroll
        for (int off = 32; off > 0; off >>= 1) m = fmaxf(m, __shfl_xor(m, off));
        const float e = expf(s - m);
        float sum = e;
        #pragma unroll
        for (int off = 32; off > 0; off >>= 1) sum += __shfl_xor(sum, off);
        mbf[(size_t)b * 4096 + c * 64 + d] = bfrne(e / sum + (c == d ? 1.f : 0.f));
    }
}

// ---------------------------------------------------------------------------
// Kernel 3 v11 (v10 with halved LDS -> higher occupancy):
// out[b,c,n] = sum_d M[c,d] * X[b, d*HW + n]
// One 32x260 buffer (33.3KB).  Two stage/MFMA phases (d 0-31 then 32-63,
// acc carries), then two store-transpose rounds (c 0-31, 32-63) through the
// same buffer.  launch_bounds(256,3): 12 waves/CU vs v10's 8.
// ---------------------------------------------------------------------------
__global__ __launch_bounds__(256, 3) void k3_out(const float* __restrict__ x,
                                                 const unsigned short* __restrict__ mbf,
                                                 float* __restrict__ out) {
    const int nbk = blockIdx.x;
    const int b   = blockIdx.y;
    const int t   = threadIdx.x;
    const int w   = t >> 6;
    const int l   = t & 63;
    const int g   = l >> 4;
    const int col = l & 15;

    __shared__ float Xs[32 * XSTRIDE];   // 33.3KB: stage + store-transpose

    const int nblk = nbk * 256;
    const float* xb = x + (size_t)b * CHW_;

    // wave w stages local rows 8w..8w+7 of the current 32-row d-phase
#define K3_STAGE(ks)                                                       \
    _Pragma("unroll")                                                      \
    for (int i = 0; i < 8; i++) {                                          \
        const int dl = 8 * w + i;                                          \
        const int p  = (w & 1) << 2;                                       \
        const float* gp = xb + (size_t)(32 * (ks) + dl) * HW_              \
                          + nblk + 4 * (l ^ p);                            \
        __builtin_amdgcn_global_load_lds(                                  \
            (const __attribute__((address_space(1))) void*)gp,             \
            (__attribute__((address_space(3))) void*)(&Xs[dl * XSTRIDE]),  \
            16, 0, 0);                                                     \
    }

    K3_STAGE(0);

    // A-fragments while staging flies (L2-hot)
    bf16x8 afr[4][2];
    const unsigned short* mb = mbf + (size_t)b * 4096;
    #pragma unroll
    for (int ct = 0; ct < 4; ct++)
        #pragma unroll
        for (int ks = 0; ks < 2; ks++)
            afr[ct][ks] = *(const bf16x8*)(mb + (16 * ct + col) * 64 + 32 * ks + 8 * g);

    f32x4v acc[4][4];
    #pragma unroll
    for (int ct = 0; ct < 4; ct++)
        #pragma unroll
        for (int nt = 0; nt < 4; nt++)
            acc[ct][nt] = (f32x4v)(0.f);

    const int psw = (g & 1) << 2;

    #pragma unroll
    for (int ks = 0; ks < 2; ks++) {
        if (ks == 1) {
            __syncthreads();     // all reads of phase-0 buffer done
            K3_STAGE(1);
        }
        __syncthreads();         // staging drained (vmcnt) before LDS reads

        #pragma unroll
        for (int nt = 0; nt < 4; nt++) {
            const int n  = 64 * w + 16 * nt + col;
            const int cn = n >> 2;
            const int eo = ((cn ^ psw) << 2) + (col & 3);

            bf16x8 bfr;
            #pragma unroll
            for (int j = 0; j < 8; j++)
                bfr[j] = (short)bfrne(Xs[(8 * g + j) * XSTRIDE + eo]);

            #pragma unroll
            for (int ct = 0; ct < 4; ct++)
                acc[ct][nt] = __builtin_amdgcn_mfma_f32_16x16x32_bf16(
                    afr[ct][ks], bfr, acc[ct][nt], 0, 0, 0);
        }
    }
#undef K3_STAGE

    // --- two store-transpose rounds through the 32-row buffer ---
    float* ob = out + (size_t)b * CHW_ + nblk;
    #pragma unroll
    for (int half = 0; half < 2; half++) {
        __syncthreads();         // previous reads/stores of Xs done
        #pragma unroll
        for (int c2 = 0; c2 < 2; c2++) {
            const int ct = 2 * half + c2;
            #pragma unroll
            for (int nt = 0; nt < 4; nt++)
                #pragma unroll
                for (int r = 0; r < 4; r++)
                    Xs[(16 * c2 + 4 * g + r) * XSTRIDE + 64 * w + 16 * nt + col] =
                        acc[ct][nt][r];
        }
        __syncthreads();
        #pragma unroll
        for (int i = 0; i < 8; i++) {
            const int row = 8 * w + i;
            const float4 v = *(const float4*)&Xs[row * XSTRIDE + 4 * l];
            *(float4*)(ob + (size_t)(32 * half + row) * HW_ + 4 * l) = v;
        }
    }
}

// ---------------------------------------------------------------------------
extern "C" void kernel_launch(void* const* d_in, const int* in_sizes, int n_in,
                              void* d_out, int out_size, void* d_ws, size_t ws_size,
                              hipStream_t stream) {
    const float* x = (const float*)d_in[0];
    float* out = (float*)d_out;

    float* wsf          = (float*)d_ws;
    unsigned short* mbf = (unsigned short*)wsf;      // B*4096 ushorts (128KB)
    float* partial      = wsf + (size_t)B_ * 4096;   // B*nch*4096 floats

    int nch = 64;
    while (nch > 1) {
        size_t need = (size_t)B_ * 4096 * sizeof(float)
                    + (size_t)B_ * nch * 4096 * sizeof(float);
        if (need <= ws_size) break;
        nch >>= 1;
    }
    const int nb = HW_ / nch;

    k1_gram<<<dim3(nch, B_), 256, 0, stream>>>(x, partial, nch, nb);
    k2_softmax<<<dim3(C_, B_), 256, 0, stream>>>(partial, mbf, nch);
    k3_out<<<dim3(HW_ / 256, B_), 256, 0, stream>>>(x, mbf, out);
}

// Round 19
// 184.115 us; speedup vs baseline: 1.3776x; 1.0528x over previous
//
#include <hip/hip_runtime.h>

#define B_   16
#define C_   64
#define HW_  65536
#define CHW_ (C_ * HW_)   // 4194304 elements per batch
#define XSTRIDE 260       // k3 LDS row stride: 1040B ≡ 0 mod 16 (b128-aligned)

typedef short bf16x8 __attribute__((ext_vector_type(8)));
typedef float f32x4v __attribute__((ext_vector_type(4)));

// fp32 -> bf16 round-to-nearest-even
__device__ __forceinline__ unsigned short bfrne(float f) {
    unsigned int u = __float_as_uint(f);
    u += 0x7FFFu + ((u >> 16) & 1u);
    return (unsigned short)(u >> 16);
}
// fp32 -> bf16 truncation (for lo residues: error <= 2^-17 relative)
__device__ __forceinline__ unsigned short bftrunc(float f) {
    return (unsigned short)(__float_as_uint(f) >> 16);
}
__device__ __forceinline__ float bfdec(unsigned short h) {
    return __uint_as_float((unsigned int)h << 16);
}

// ---------------------------------------------------------------------------
// Kernel 1 v9 (v8 + lo-truncation): split-bf16 MFMA;
// S[b,c,d] = sum_n A[c][n]*B[n][d]; S ~= hh+hl+lh.
// B staged via global_load_lds (ping-pong LDS), A ping-pongs through regs.
// ---------------------------------------------------------------------------
__global__ __launch_bounds__(256, 2) void k1_gram(const float* __restrict__ x,
                                                  float* __restrict__ partial,
                                                  int nch, int nb) {
    const int ch  = blockIdx.x;
    const int b   = blockIdx.y;
    const int t   = threadIdx.x;
    const int w   = t >> 6;
    const int l   = t & 63;
    const int g   = l >> 4;
    const int col = l & 15;

    __shared__ float Bs[4][2][2048];   // [wave][pingpong][32n x 64d], 64KB

    const float* xb = x + (size_t)b * CHW_;
    const int nq  = nb >> 2;
    const int nw0 = ch * nb + w * nq;
    const int nit = nq >> 5;           // 16 at nch=32 (even)

#define K1_STAGE(dst, ns)                                                  \
    {                                                                      \
        const float* bsrc = xb + (size_t)(ns) * C_;                        \
        _Pragma("unroll")                                                  \
        for (int i = 0; i < 8; i++) {                                      \
            const int sw = (i >> 1) << 2;                                  \
            const float* gp = bsrc + 256 * i + 64 * (l >> 4)               \
                              + 4 * ((l & 15) ^ sw);                       \
            __builtin_amdgcn_global_load_lds(                              \
                (const __attribute__((address_space(1))) void*)gp,         \
                (__attribute__((address_space(3))) void*)((dst) + 256 * i),\
                16, 0, 0);                                                 \
        }                                                                  \
    }

#define K1_LOADA(AV, ns)                                                   \
    _Pragma("unroll")                                                      \
    for (int ct = 0; ct < 4; ct++) {                                       \
        const float* ap = xb + (size_t)(16 * ct + col) * HW_ + (ns) + 8 * g; \
        *(float4*)&AV[ct][0] = *(const float4*)ap;                         \
        *(float4*)&AV[ct][4] = *(const float4*)(ap + 4);                   \
    }

#define K1_CONVA(AV)                                                       \
    _Pragma("unroll")                                                      \
    for (int ct = 0; ct < 4; ct++)                                         \
        _Pragma("unroll")                                                  \
        for (int j = 0; j < 8; j++) {                                      \
            const unsigned short h = bfrne(AV[ct][j]);                     \
            ahi[ct][j] = (short)h;                                         \
            alo[ct][j] = (short)bftrunc(AV[ct][j] - bfdec(h));             \
        }

#define K1_BPHASE(cur)                                                     \
    _Pragma("unroll")                                                      \
    for (int dt = 0; dt < 4; dt++) {                                       \
        const int eo = 16 * (dt ^ g) + col;                                \
        float bv[8];                                                       \
        _Pragma("unroll")                                                  \
        for (int j = 0; j < 8; j++) bv[j] = (cur)[(8 * g + j) * 64 + eo];  \
        bf16x8 bhi, blo;                                                   \
        _Pragma("unroll")                                                  \
        for (int j = 0; j < 8; j++) {                                      \
            const unsigned short h = bfrne(bv[j]);                         \
            bhi[j] = (short)h;                                             \
            blo[j] = (short)bftrunc(bv[j] - bfdec(h));                     \
        }                                                                  \
        _Pragma("unroll")                                                  \
        for (int ct = 0; ct < 4; ct++) {                                   \
            acc[ct][dt] = __builtin_amdgcn_mfma_f32_16x16x32_bf16(         \
                ahi[ct], bhi, acc[ct][dt], 0, 0, 0);                       \
            acc[ct][dt] = __builtin_amdgcn_mfma_f32_16x16x32_bf16(         \
                ahi[ct], blo, acc[ct][dt], 0, 0, 0);                       \
            acc[ct][dt] = __builtin_amdgcn_mfma_f32_16x16x32_bf16(         \
                alo[ct], bhi, acc[ct][dt], 0, 0, 0);                       \
        }                                                                  \
    }

    f32x4v acc[4][4];
    #pragma unroll
    for (int ct = 0; ct < 4; ct++)
        #pragma unroll
        for (int dt = 0; dt < 4; dt++) acc[ct][dt] = (f32x4v)(0.f);

    float avA[4][8], avB[4][8];
    bf16x8 ahi[4], alo[4];

    K1_STAGE(Bs[w][0], nw0);
    K1_LOADA(avA, nw0);

    for (int it2 = 0; it2 < nit; it2 += 2) {
        {
            const int ns = nw0 + (it2 << 5);
            K1_LOADA(avB, ns + 32);
            K1_STAGE(Bs[w][1], ns + 32);
            K1_CONVA(avA);
            asm volatile("s_waitcnt vmcnt(16)" ::: "memory");
            K1_BPHASE(Bs[w][0]);
        }
        {
            const int ns = nw0 + ((it2 + 1) << 5);
            if (it2 + 2 < nit) {
                K1_LOADA(avA, ns + 32);
                K1_STAGE(Bs[w][0], ns + 32);
            }
            K1_CONVA(avB);
            if (it2 + 2 < nit) asm volatile("s_waitcnt vmcnt(16)" ::: "memory");
            else               asm volatile("s_waitcnt vmcnt(0)"  ::: "memory");
            K1_BPHASE(Bs[w][1]);
        }
    }
#undef K1_STAGE
#undef K1_LOADA
#undef K1_CONVA
#undef K1_BPHASE

    float* sred = (float*)Bs;
    for (int wr = 0; wr < 4; wr++) {
        if (w == wr) {
            #pragma unroll
            for (int ct = 0; ct < 4; ct++)
                #pragma unroll
                for (int dt = 0; dt < 4; dt++)
                    #pragma unroll
                    for (int r = 0; r < 4; r++) {
                        const int idx = (16 * ct + 4 * g + r) * 64 + 16 * dt + col;
                        if (wr == 0) sred[idx] = acc[ct][dt][r];
                        else         sred[idx] += acc[ct][dt][r];
                    }
        }
        __syncthreads();
    }

    float* pb = partial + (size_t)(b * nch + ch) * 4096;
    for (int i = 4 * t; i < 4096; i += 1024)
        *(float4*)&pb[i] = *(const float4*)&sred[i];
}

// ---------------------------------------------------------------------------
// Kernel 2 v3: reduce partials + softmax (unchanged; nch now 32).
// ---------------------------------------------------------------------------
__global__ __launch_bounds__(256) void k2_softmax(const float* __restrict__ partial,
                                                  unsigned short* __restrict__ mbf,
                                                  int nch) {
    const int c = blockIdx.x;
    const int b = blockIdx.y;
    const int t = threadIdx.x;
    const int w = t >> 6;
    const int d = t & 63;

    float s = 0.f;
    for (int ch = w; ch < nch; ch += 4)
        s += partial[(size_t)(b * nch + ch) * 4096 + c * 64 + d];

    __shared__ float red[256];
    red[t] = s;
    __syncthreads();
    if (w == 0) {
        s = red[d] + red[64 + d] + red[128 + d] + red[192 + d];
        float m = s;
        #pragma unroll
        for (int off = 32; off > 0; off >>= 1) m = fmaxf(m, __shfl_xor(m, off));
        const float e = expf(s - m);
        float sum = e;
        #pragma unroll
        for (int off = 32; off > 0; off >>= 1) sum += __shfl_xor(sum, off);
        mbf[(size_t)b * 4096 + c * 64 + d] = bfrne(e / sum + (c == d ? 1.f : 0.f));
    }
}

// ---------------------------------------------------------------------------
// Kernel 3 v11 (unchanged from R18 — ~80us): 32-row phased staging,
// launch_bounds(256,3), LDS-transpose coalesced stores.
// ---------------------------------------------------------------------------
__global__ __launch_bounds__(256, 3) void k3_out(const float* __restrict__ x,
                                                 const unsigned short* __restrict__ mbf,
                                                 float* __restrict__ out) {
    const int nbk = blockIdx.x;
    const int b   = blockIdx.y;
    const int t   = threadIdx.x;
    const int w   = t >> 6;
    const int l   = t & 63;
    const int g   = l >> 4;
    const int col = l & 15;

    __shared__ float Xs[32 * XSTRIDE];   // 33.3KB: stage + store-transpose

    const int nblk = nbk * 256;
    const float* xb = x + (size_t)b * CHW_;

#define K3_STAGE(ks)                                                       \
    _Pragma("unroll")                                                      \
    for (int i = 0; i < 8; i++) {                                          \
        const int dl = 8 * w + i;                                          \
        const int p  = (w & 1) << 2;                                       \
        const float* gp = xb + (size_t)(32 * (ks) + dl) * HW_              \
                          + nblk + 4 * (l ^ p);                            \
        __builtin_amdgcn_global_load_lds(                                  \
            (const __attribute__((address_space(1))) void*)gp,             \
            (__attribute__((address_space(3))) void*)(&Xs[dl * XSTRIDE]),  \
            16, 0, 0);                                                     \
    }

    K3_STAGE(0);

    bf16x8 afr[4][2];
    const unsigned short* mb = mbf + (size_t)b * 4096;
    #pragma unroll
    for (int ct = 0; ct < 4; ct++)
        #pragma unroll
        for (int ks = 0; ks < 2; ks++)
            afr[ct][ks] = *(const bf16x8*)(mb + (16 * ct + col) * 64 + 32 * ks + 8 * g);

    f32x4v acc[4][4];
    #pragma unroll
    for (int ct = 0; ct < 4; ct++)
        #pragma unroll
        for (int nt = 0; nt < 4; nt++)
            acc[ct][nt] = (f32x4v)(0.f);

    const int psw = (g & 1) << 2;

    #pragma unroll
    for (int ks = 0; ks < 2; ks++) {
        if (ks == 1) {
            __syncthreads();
            K3_STAGE(1);
        }
        __syncthreads();

        #pragma unroll
        for (int nt = 0; nt < 4; nt++) {
            const int n  = 64 * w + 16 * nt + col;
            const int cn = n >> 2;
            const int eo = ((cn ^ psw) << 2) + (col & 3);

            bf16x8 bfr;
            #pragma unroll
            for (int j = 0; j < 8; j++)
                bfr[j] = (short)bfrne(Xs[(8 * g + j) * XSTRIDE + eo]);

            #pragma unroll
            for (int ct = 0; ct < 4; ct++)
                acc[ct][nt] = __builtin_amdgcn_mfma_f32_16x16x32_bf16(
                    afr[ct][ks], bfr, acc[ct][nt], 0, 0, 0);
        }
    }
#undef K3_STAGE

    float* ob = out + (size_t)b * CHW_ + nblk;
    #pragma unroll
    for (int half = 0; half < 2; half++) {
        __syncthreads();
        #pragma unroll
        for (int c2 = 0; c2 < 2; c2++) {
            const int ct = 2 * half + c2;
            #pragma unroll
            for (int nt = 0; nt < 4; nt++)
                #pragma unroll
                for (int r = 0; r < 4; r++)
                    Xs[(16 * c2 + 4 * g + r) * XSTRIDE + 64 * w + 16 * nt + col] =
                        acc[ct][nt][r];
        }
        __syncthreads();
        #pragma unroll
        for (int i = 0; i < 8; i++) {
            const int row = 8 * w + i;
            const float4 v = *(const float4*)&Xs[row * XSTRIDE + 4 * l];
            *(float4*)(ob + (size_t)(32 * half + row) * HW_ + 4 * l) = v;
        }
    }
}

// ---------------------------------------------------------------------------
extern "C" void kernel_launch(void* const* d_in, const int* in_sizes, int n_in,
                              void* d_out, int out_size, void* d_ws, size_t ws_size,
                              hipStream_t stream) {
    const float* x = (const float*)d_in[0];
    float* out = (float*)d_out;

    float* wsf          = (float*)d_ws;
    unsigned short* mbf = (unsigned short*)wsf;      // B*4096 ushorts (128KB)
    float* partial      = wsf + (size_t)B_ * 4096;   // B*nch*4096 floats

    int nch = 32;
    while (nch > 1) {
        size_t need = (size_t)B_ * 4096 * sizeof(float)
                    + (size_t)B_ * nch * 4096 * sizeof(float);
        if (need <= ws_size) break;
        nch >>= 1;
    }
    const int nb = HW_ / nch;

    k1_gram<<<dim3(nch, B_), 256, 0, stream>>>(x, partial, nch, nb);
    k2_softmax<<<dim3(C_, B_), 256, 0, stream>>>(partial, mbf, nch);
    k3_out<<<dim3(HW_ / 256, B_), 256, 0, stream>>>(x, mbf, out);
}

// Round 20
// 183.222 us; speedup vs baseline: 1.3843x; 1.0049x over previous
//
#include <hip/hip_runtime.h>

#define B_   16
#define C_   64
#define HW_  65536
#define CHW_ (C_ * HW_)   // 4194304 elements per batch
#define XSTRIDE 260       // k3 LDS row stride: 1040B ≡ 0 mod 16 (b128-aligned)

typedef short bf16x8 __attribute__((ext_vector_type(8)));
typedef float f32x4v __attribute__((ext_vector_type(4)));

// fp32 -> bf16 round-to-nearest-even
__device__ __forceinline__ unsigned short bfrne(float f) {
    unsigned int u = __float_as_uint(f);
    u += 0x7FFFu + ((u >> 16) & 1u);
    return (unsigned short)(u >> 16);
}
// fp32 -> bf16 truncation (for lo residues: error <= 2^-17 relative)
__device__ __forceinline__ unsigned short bftrunc(float f) {
    return (unsigned short)(__float_as_uint(f) >> 16);
}
__device__ __forceinline__ float bfdec(unsigned short h) {
    return __uint_as_float((unsigned int)h << 16);
}

// ---------------------------------------------------------------------------
// Kernel 1 v10 (v9 + setprio around MFMA clusters): split-bf16 MFMA;
// S[b,c,d] = sum_n A[c][n]*B[n][d]; S ~= hh+hl+lh.
// Main loop has no block barriers -> waves phase-stagger; setprio(1) biases
// the CU scheduler toward the wave in its MFMA phase (T5, m191 pattern).
// ---------------------------------------------------------------------------
__global__ __launch_bounds__(256, 2) void k1_gram(const float* __restrict__ x,
                                                  float* __restrict__ partial,
                                                  int nch, int nb) {
    const int ch  = blockIdx.x;
    const int b   = blockIdx.y;
    const int t   = threadIdx.x;
    const int w   = t >> 6;
    const int l   = t & 63;
    const int g   = l >> 4;
    const int col = l & 15;

    __shared__ float Bs[4][2][2048];   // [wave][pingpong][32n x 64d], 64KB

    const float* xb = x + (size_t)b * CHW_;
    const int nq  = nb >> 2;
    const int nw0 = ch * nb + w * nq;
    const int nit = nq >> 5;           // 16 at nch=32 (even)

#define K1_STAGE(dst, ns)                                                  \
    {                                                                      \
        const float* bsrc = xb + (size_t)(ns) * C_;                        \
        _Pragma("unroll")                                                  \
        for (int i = 0; i < 8; i++) {                                      \
            const int sw = (i >> 1) << 2;                                  \
            const float* gp = bsrc + 256 * i + 64 * (l >> 4)               \
                              + 4 * ((l & 15) ^ sw);                       \
            __builtin_amdgcn_global_load_lds(                              \
                (const __attribute__((address_space(1))) void*)gp,         \
                (__attribute__((address_space(3))) void*)((dst) + 256 * i),\
                16, 0, 0);                                                 \
        }                                                                  \
    }

#define K1_LOADA(AV, ns)                                                   \
    _Pragma("unroll")                                                      \
    for (int ct = 0; ct < 4; ct++) {                                       \
        const float* ap = xb + (size_t)(16 * ct + col) * HW_ + (ns) + 8 * g; \
        *(float4*)&AV[ct][0] = *(const float4*)ap;                         \
        *(float4*)&AV[ct][4] = *(const float4*)(ap + 4);                   \
    }

#define K1_CONVA(AV)                                                       \
    _Pragma("unroll")                                                      \
    for (int ct = 0; ct < 4; ct++)                                         \
        _Pragma("unroll")                                                  \
        for (int j = 0; j < 8; j++) {                                      \
            const unsigned short h = bfrne(AV[ct][j]);                     \
            ahi[ct][j] = (short)h;                                         \
            alo[ct][j] = (short)bftrunc(AV[ct][j] - bfdec(h));             \
        }

#define K1_BPHASE(cur)                                                     \
    _Pragma("unroll")                                                      \
    for (int dt = 0; dt < 4; dt++) {                                       \
        const int eo = 16 * (dt ^ g) + col;                                \
        float bv[8];                                                       \
        _Pragma("unroll")                                                  \
        for (int j = 0; j < 8; j++) bv[j] = (cur)[(8 * g + j) * 64 + eo];  \
        bf16x8 bhi, blo;                                                   \
        _Pragma("unroll")                                                  \
        for (int j = 0; j < 8; j++) {                                      \
            const unsigned short h = bfrne(bv[j]);                         \
            bhi[j] = (short)h;                                             \
            blo[j] = (short)bftrunc(bv[j] - bfdec(h));                     \
        }                                                                  \
        __builtin_amdgcn_s_setprio(1);                                     \
        _Pragma("unroll")                                                  \
        for (int ct = 0; ct < 4; ct++) {                                   \
            acc[ct][dt] = __builtin_amdgcn_mfma_f32_16x16x32_bf16(         \
                ahi[ct], bhi, acc[ct][dt], 0, 0, 0);                       \
            acc[ct][dt] = __builtin_amdgcn_mfma_f32_16x16x32_bf16(         \
                ahi[ct], blo, acc[ct][dt], 0, 0, 0);                       \
            acc[ct][dt] = __builtin_amdgcn_mfma_f32_16x16x32_bf16(         \
                alo[ct], bhi, acc[ct][dt], 0, 0, 0);                       \
        }                                                                  \
        __builtin_amdgcn_s_setprio(0);                                     \
    }

    f32x4v acc[4][4];
    #pragma unroll
    for (int ct = 0; ct < 4; ct++)
        #pragma unroll
        for (int dt = 0; dt < 4; dt++) acc[ct][dt] = (f32x4v)(0.f);

    float avA[4][8], avB[4][8];
    bf16x8 ahi[4], alo[4];

    K1_STAGE(Bs[w][0], nw0);
    K1_LOADA(avA, nw0);

    for (int it2 = 0; it2 < nit; it2 += 2) {
        {
            const int ns = nw0 + (it2 << 5);
            K1_LOADA(avB, ns + 32);
            K1_STAGE(Bs[w][1], ns + 32);
            K1_CONVA(avA);
            asm volatile("s_waitcnt vmcnt(16)" ::: "memory");
            K1_BPHASE(Bs[w][0]);
        }
        {
            const int ns = nw0 + ((it2 + 1) << 5);
            if (it2 + 2 < nit) {
                K1_LOADA(avA, ns + 32);
                K1_STAGE(Bs[w][0], ns + 32);
            }
            K1_CONVA(avB);
            if (it2 + 2 < nit) asm volatile("s_waitcnt vmcnt(16)" ::: "memory");
            else               asm volatile("s_waitcnt vmcnt(0)"  ::: "memory");
            K1_BPHASE(Bs[w][1]);
        }
    }
#undef K1_STAGE
#undef K1_LOADA
#undef K1_CONVA
#undef K1_BPHASE

    float* sred = (float*)Bs;
    for (int wr = 0; wr < 4; wr++) {
        if (w == wr) {
            #pragma unroll
            for (int ct = 0; ct < 4; ct++)
                #pragma unroll
                for (int dt = 0; dt < 4; dt++)
                    #pragma unroll
                    for (int r = 0; r < 4; r++) {
                        const int idx = (16 * ct + 4 * g + r) * 64 + 16 * dt + col;
                        if (wr == 0) sred[idx] = acc[ct][dt][r];
                        else         sred[idx] += acc[ct][dt][r];
                    }
        }
        __syncthreads();
    }

    float* pb = partial + (size_t)(b * nch + ch) * 4096;
    for (int i = 4 * t; i < 4096; i += 1024)
        *(float4*)&pb[i] = *(const float4*)&sred[i];
}

// ---------------------------------------------------------------------------
// Kernel 2 v3: reduce partials + softmax (unchanged; nch=32).
// ---------------------------------------------------------------------------
__global__ __launch_bounds__(256) void k2_softmax(const float* __restrict__ partial,
                                                  unsigned short* __restrict__ mbf,
                                                  int nch) {
    const int c = blockIdx.x;
    const int b = blockIdx.y;
    const int t = threadIdx.x;
    const int w = t >> 6;
    const int d = t & 63;

    float s = 0.f;
    for (int ch = w; ch < nch; ch += 4)
        s += partial[(size_t)(b * nch + ch) * 4096 + c * 64 + d];

    __shared__ float red[256];
    red[t] = s;
    __syncthreads();
    if (w == 0) {
        s = red[d] + red[64 + d] + red[128 + d] + red[192 + d];
        float m = s;
        #pragma unroll
        for (int off = 32; off > 0; off >>= 1) m = fmaxf(m, __shfl_xor(m, off));
        const float e = expf(s - m);
        float sum = e;
        #pragma unroll
        for (int off = 32; off > 0; off >>= 1) sum += __shfl_xor(sum, off);
        mbf[(size_t)b * 4096 + c * 64 + d] = bfrne(e / sum + (c == d ? 1.f : 0.f));
    }
}

// ---------------------------------------------------------------------------
// Kernel 3 v12 (v11 + setprio around MFMA clusters): 32-row phased staging,
// launch_bounds(256,3), LDS-transpose coalesced stores.
// ---------------------------------------------------------------------------
__global__ __launch_bounds__(256, 3) void k3_out(const float* __restrict__ x,
                                                 const unsigned short* __restrict__ mbf,
                                                 float* __restrict__ out) {
    const int nbk = blockIdx.x;
    const int b   = blockIdx.y;
    const int t   = threadIdx.x;
    const int w   = t >> 6;
    const int l   = t & 63;
    const int g   = l >> 4;
    const int col = l & 15;

    __shared__ float Xs[32 * XSTRIDE];   // 33.3KB: stage + store-transpose

    const int nblk = nbk * 256;
    const float* xb = x + (size_t)b * CHW_;

#define K3_STAGE(ks)                                                       \
    _Pragma("unroll")                                                      \
    for (int i = 0; i < 8; i++) {                                          \
        const int dl = 8 * w + i;                                          \
        const int p  = (w & 1) << 2;                                       \
        const float* gp = xb + (size_t)(32 * (ks) + dl) * HW_              \
                          + nblk + 4 * (l ^ p);                            \
        __builtin_amdgcn_global_load_lds(                                  \
            (const __attribute__((address_space(1))) void*)gp,             \
            (__attribute__((address_space(3))) void*)(&Xs[dl * XSTRIDE]),  \
            16, 0, 0);                                                     \
    }

    K3_STAGE(0);

    bf16x8 afr[4][2];
    const unsigned short* mb = mbf + (size_t)b * 4096;
    #pragma unroll
    for (int ct = 0; ct < 4; ct++)
        #pragma unroll
        for (int ks = 0; ks < 2; ks++)
            afr[ct][ks] = *(const bf16x8*)(mb + (16 * ct + col) * 64 + 32 * ks + 8 * g);

    f32x4v acc[4][4];
    #pragma unroll
    for (int ct = 0; ct < 4; ct++)
        #pragma unroll
        for (int nt = 0; nt < 4; nt++)
            acc[ct][nt] = (f32x4v)(0.f);

    const int psw = (g & 1) << 2;

    #pragma unroll
    for (int ks = 0; ks < 2; ks++) {
        if (ks == 1) {
            __syncthreads();
            K3_STAGE(1);
        }
        __syncthreads();

        #pragma unroll
        for (int nt = 0; nt < 4; nt++) {
            const int n  = 64 * w + 16 * nt + col;
            const int cn = n >> 2;
            const int eo = ((cn ^ psw) << 2) + (col & 3);

            bf16x8 bfr;
            #pragma unroll
            for (int j = 0; j < 8; j++)
                bfr[j] = (short)bfrne(Xs[(8 * g + j) * XSTRIDE + eo]);

            __builtin_amdgcn_s_setprio(1);
            #pragma unroll
            for (int ct = 0; ct < 4; ct++)
                acc[ct][nt] = __builtin_amdgcn_mfma_f32_16x16x32_bf16(
                    afr[ct][ks], bfr, acc[ct][nt], 0, 0, 0);
            __builtin_amdgcn_s_setprio(0);
        }
    }
#undef K3_STAGE

    float* ob = out + (size_t)b * CHW_ + nblk;
    #pragma unroll
    for (int half = 0; half < 2; half++) {
        __syncthreads();
        #pragma unroll
        for (int c2 = 0; c2 < 2; c2++) {
            const int ct = 2 * half + c2;
            #pragma unroll
            for (int nt = 0; nt < 4; nt++)
                #pragma unroll
                for (int r = 0; r < 4; r++)
                    Xs[(16 * c2 + 4 * g + r) * XSTRIDE + 64 * w + 16 * nt + col] =
                        acc[ct][nt][r];
        }
        __syncthreads();
        #pragma unroll
        for (int i = 0; i < 8; i++) {
            const int row = 8 * w + i;
            const float4 v = *(const float4*)&Xs[row * XSTRIDE + 4 * l];
            *(float4*)(ob + (size_t)(32 * half + row) * HW_ + 4 * l) = v;
        }
    }
}

// ---------------------------------------------------------------------------
extern "C" void kernel_launch(void* const* d_in, const int* in_sizes, int n_in,
                              void* d_out, int out_size, void* d_ws, size_t ws_size,
                              hipStream_t stream) {
    const float* x = (const float*)d_in[0];
    float* out = (float*)d_out;

    float* wsf          = (float*)d_ws;
    unsigned short* mbf = (unsigned short*)wsf;      // B*4096 ushorts (128KB)
    float* partial      = wsf + (size_t)B_ * 4096;   // B*nch*4096 floats

    int nch = 32;
    while (nch > 1) {
        size_t need = (size_t)B_ * 4096 * sizeof(float)
                    + (size_t)B_ * nch * 4096 * sizeof(float);
        if (need <= ws_size) break;
        nch >>= 1;
    }
    const int nb = HW_ / nch;

    k1_gram<<<dim3(nch, B_), 256, 0, stream>>>(x, partial, nch, nb);
    k2_softmax<<<dim3(C_, B_), 256, 0, stream>>>(partial, mbf, nch);
    k3_out<<<dim3(HW_ / 256, B_), 256, 0, stream>>>(x, mbf, out);
}